// Round 2
// baseline (6246.830 us; speedup 1.0000x reference)
//
#include <hip/hip_runtime.h>
#include <hip/hip_bf16.h>
#include <math.h>

#define N_NODES 16000
#define N_EDGES 128000
#define N_GRAPH 64
#define NL 5
#define EPSV 1e-5f
#define SCALE 0.07216878364870323f   // 1/sqrt(192)

#define PC 2048      // P cols (bf16): [0,256)=Q | [256,512)=K | [512,1280)=VdT | [1280,2048)=VsT
#define ECOLS 1024   // EP cols (bf16): [0,256)=Eh | [256,1024)=EhT (bupd folded into bias)

typedef __hip_bfloat16 bf16;

// ---------------- weight packing ----------------
__global__ void pack_w(const float* __restrict__ Wq, const float* __restrict__ Wk,
                       const float* __restrict__ Wv, const float* __restrict__ Wupd,
                       const float* __restrict__ Wedge,
                       float* __restrict__ Wnp, float* __restrict__ Wep) {
    int idx = blockIdx.x * 256 + threadIdx.x;
    int total = NL * 64 * (PC + ECOLS);
    if (idx >= total) return;
    int c = idx % (PC + ECOLS);
    int j = (idx / (PC + ECOLS)) % 64;
    int l = idx / (64 * (PC + ECOLS));
    if (c < PC) {
        float v = 0.f;
        if (c < 256) v = Wq[(l*64 + j)*256 + c];
        else if (c < 512) v = Wk[(l*64 + j)*256 + (c - 256)];
        else if (c < 1280) {
            int cc = c - 512, hd = cc / 192, p = cc % 192;
            float s = 0.f;
            for (int k = 0; k < 64; ++k)
                s += Wv[(l*64 + j)*256 + hd*64 + k] * Wupd[(l*192 + k)*192 + p];
            v = s;
        } else {
            int cc = c - 1280, hd = cc / 192, p = cc % 192;
            float s = 0.f;
            for (int k = 0; k < 64; ++k)
                s += Wv[(l*64 + j)*256 + hd*64 + k] * Wupd[(l*192 + 64 + k)*192 + p];
            v = s;
        }
        Wnp[(size_t)(l*64 + j)*PC + c] = v;
    } else {
        int ce = c - PC;
        float v;
        if (ce < 256) v = Wedge[(l*64 + j)*256 + ce];
        else {
            int cc = ce - 256, hd = cc / 192, p = cc % 192;
            float s = 0.f;
            for (int k = 0; k < 64; ++k)
                s += Wedge[(l*64 + j)*256 + hd*64 + k] * Wupd[(l*192 + 128 + k)*192 + p];
            v = s;
        }
        Wep[(size_t)(l*64 + j)*ECOLS + ce] = v;
    }
}

__global__ void pack_b(const float* __restrict__ bq, const float* __restrict__ bk,
                       const float* __restrict__ bv, const float* __restrict__ Wupd,
                       const float* __restrict__ bupd, const float* __restrict__ bedge,
                       float* __restrict__ bnp, float* __restrict__ bep) {
    int idx = blockIdx.x * 256 + threadIdx.x;
    int total = NL * (PC + ECOLS);
    if (idx >= total) return;
    int c = idx % (PC + ECOLS);
    int l = idx / (PC + ECOLS);
    if (c < PC) {
        float v = 0.f;
        if (c < 256) v = bq[l*256 + c];
        else if (c < 512) v = bk[l*256 + c - 256];
        else if (c < 1280) {
            int cc = c - 512, hd = cc / 192, p = cc % 192;
            float s = 0.f;
            for (int k = 0; k < 64; ++k) s += bv[l*256 + hd*64 + k] * Wupd[(l*192 + k)*192 + p];
            v = s;
        } else {
            int cc = c - 1280, hd = cc / 192, p = cc % 192;
            float s = 0.f;
            for (int k = 0; k < 64; ++k) s += bv[l*256 + hd*64 + k] * Wupd[(l*192 + 64 + k)*192 + p];
            v = s;
        }
        bnp[l*PC + c] = v;
    } else {
        int ce = c - PC;
        float v;
        if (ce < 256) v = bedge[l*256 + ce];
        else {
            int cc = ce - 256, hd = cc / 192, p = cc % 192;
            float s = bupd[l*192 + p];  // fold bupd here
            for (int k = 0; k < 64; ++k) s += bedge[l*256 + hd*64 + k] * Wupd[(l*192 + 128 + k)*192 + p];
            v = s;
        }
        bep[l*ECOLS + ce] = v;
    }
}

// ---------------- initial embeddings ----------------
__global__ void init_h(const float* __restrict__ x, const float* __restrict__ W_atom,
                       const float* __restrict__ b_atom, float* __restrict__ h) {
    int idx = blockIdx.x * 256 + threadIdx.x;   // N*64
    int d = idx & 63, n = idx >> 6;
    float s = b_atom[d];
    #pragma unroll
    for (int j = 0; j < 4; ++j) s += x[n*4 + j] * W_atom[j*64 + d];
    h[idx] = s;
}

__global__ void init_e(const float* __restrict__ ea, const float* __restrict__ We1,
                       const float* __restrict__ be1, const float* __restrict__ We2,
                       const float* __restrict__ be2, float* __restrict__ ef) {
    __shared__ float sT[4][64];
    int tid = threadIdx.x, d = tid & 63, sub = tid >> 6;
    int e = blockIdx.x * 4 + sub;
    float s = be1[d];
    #pragma unroll
    for (int j = 0; j < 9; ++j) s += ea[e*9 + j] * We1[j*64 + d];
    // softplus beta=64 threshold=64
    float x64 = s * 64.f;
    float sp = (x64 > 64.f) ? s : log1pf(__expf(fminf(x64, 64.f))) * (1.f/64.f);
    sT[sub][d] = sp;   // wave-local: same wave writes then reads
    float acc = be2[d];
    #pragma unroll
    for (int k = 0; k < 64; ++k) acc += sT[sub][k] * We2[k*64 + d];
    ef[(size_t)e*64 + d] = acc;
}

// ---------------- rank-64 projection: out_bf16[rows,M] = A_f32[rows,64]@W[64,M] + b ----------------
__global__ __launch_bounds__(256, 2) void proj_gemm(
    const float* __restrict__ A, const float* __restrict__ W, const float* __restrict__ bias,
    bf16* __restrict__ out, int rows, int M) {
    __shared__ float sW[64 * 256];
    __shared__ __align__(16) float sA[4][64];
    int tid = threadIdx.x;
    int c = blockIdx.x * 256 + tid;
    for (int j = 0; j < 64; ++j) sW[j*256 + tid] = W[(size_t)j*M + c];
    float bv = bias[c];
    __syncthreads();
    for (int r0 = blockIdx.y * 4; r0 < rows; r0 += gridDim.y * 4) {
        sA[tid >> 6][tid & 63] = A[(size_t)(r0 + (tid >> 6))*64 + (tid & 63)];
        __syncthreads();
        float a0 = bv, a1 = bv, a2 = bv, a3 = bv;
        #pragma unroll
        for (int j4 = 0; j4 < 16; ++j4) {
            float4 r0v = *(const float4*)&sA[0][j4*4];
            float4 r1v = *(const float4*)&sA[1][j4*4];
            float4 r2v = *(const float4*)&sA[2][j4*4];
            float4 r3v = *(const float4*)&sA[3][j4*4];
            float w0 = sW[(j4*4+0)*256 + tid], w1 = sW[(j4*4+1)*256 + tid];
            float w2 = sW[(j4*4+2)*256 + tid], w3 = sW[(j4*4+3)*256 + tid];
            a0 += r0v.x*w0 + r0v.y*w1 + r0v.z*w2 + r0v.w*w3;
            a1 += r1v.x*w0 + r1v.y*w1 + r1v.z*w2 + r1v.w*w3;
            a2 += r2v.x*w0 + r2v.y*w1 + r2v.z*w2 + r2v.w*w3;
            a3 += r3v.x*w0 + r3v.y*w1 + r3v.z*w2 + r3v.w*w3;
        }
        out[(size_t)(r0+0)*M + c] = __float2bfloat16(a0);
        out[(size_t)(r0+1)*M + c] = __float2bfloat16(a1);
        out[(size_t)(r0+2)*M + c] = __float2bfloat16(a2);
        out[(size_t)(r0+3)*M + c] = __float2bfloat16(a3);
        __syncthreads();
    }
}

// ---------------- HF = h @ Wfea + bfea (f32, residual path) ----------------
__global__ __launch_bounds__(256) void hf_proj(const float* __restrict__ h,
                                               const float* __restrict__ Wfea,
                                               const float* __restrict__ bfea,
                                               float* __restrict__ HF) {
    __shared__ float sW[64*64];
    __shared__ __align__(16) float sA[4][64];
    int tid = threadIdx.x;
    for (int i = tid; i < 4096; i += 256) sW[i] = Wfea[i];
    int c = tid & 63, no = tid >> 6;
    int n0 = blockIdx.x * 4;
    sA[no][c] = h[(size_t)(n0 + no)*64 + c];
    __syncthreads();
    float acc = bfea[c];
    #pragma unroll
    for (int k4 = 0; k4 < 16; ++k4) {
        float4 av = *(const float4*)&sA[no][k4*4];
        acc += av.x*sW[(k4*4+0)*64+c] + av.y*sW[(k4*4+1)*64+c]
             + av.z*sW[(k4*4+2)*64+c] + av.w*sW[(k4*4+3)*64+c];
    }
    HF[(size_t)(n0 + no)*64 + c] = acc;
}

// ---------------- fused per-edge attention/gating/message ----------------
__global__ __launch_bounds__(512, 4) void edge_fused(
    const bf16* __restrict__ P, const bf16* __restrict__ EP,
    const int* __restrict__ ei, int chunk_base,
    const float* __restrict__ Wmsg, const float* __restrict__ bmsg,
    const float* __restrict__ g_ln, const float* __restrict__ be_ln,
    const float* __restrict__ g_msg, const float* __restrict__ be_msg,
    float* __restrict__ agg) {
    __shared__ float sW[192 * 64];
    __shared__ __align__(16) float sM[8][4][192];
    int tid = threadIdx.x;
    for (int i = tid; i < 192*64; i += 512) sW[i] = Wmsg[i];
    int lane = tid & 63, w = tid >> 6, hd = w & 3;
    float gl0 = g_ln[lane], gl1 = g_ln[64 + lane], gl2 = g_ln[128 + lane];
    float bl0 = be_ln[lane], bl1 = be_ln[64 + lane], bl2 = be_ln[128 + lane];
    float gm = g_msg[lane], bm = be_msg[lane], bms = bmsg[lane];
    __syncthreads();
    int e0 = blockIdx.x * 8 + (w >> 2) * 4;   // this wave: 4 edges, head hd
    int dstv[4];
    #pragma unroll
    for (int it = 0; it < 4; ++it) {
        int el = e0 + it, eg = chunk_base + el;
        int src = ei[eg], dst = ei[N_EDGES + eg];
        dstv[it] = dst;
        const bf16* Pd = P + (size_t)dst * PC;
        const bf16* Ps = P + (size_t)src * PC;
        const bf16* Ee = EP + (size_t)el * ECOLS;
        float q  = __bfloat162float(Pd[hd*64 + lane]);
        float kd = __bfloat162float(Pd[256 + hd*64 + lane]);
        float ks = __bfloat162float(Ps[256 + hd*64 + lane]);
        float eh = __bfloat162float(Ee[hd*64 + lane]);
        float a0 = q*kd*SCALE, a1 = q*ks*SCALE, a2 = q*eh*SCALE;
        float s = a0 + a1 + a2, ss = a0*a0 + a1*a1 + a2*a2;
        #pragma unroll
        for (int m = 1; m < 64; m <<= 1) { s += __shfl_xor(s, m); ss += __shfl_xor(ss, m); }
        float mu = s * (1.f/192.f);
        float var = ss * (1.f/192.f) - mu*mu;
        float rstd = rsqrtf(var + EPSV);
        float g0 = 1.f/(1.f + __expf(-((a0 - mu)*rstd*gl0 + bl0)));
        float g1 = 1.f/(1.f + __expf(-((a1 - mu)*rstd*gl1 + bl1)));
        float g2 = 1.f/(1.f + __expf(-((a2 - mu)*rstd*gl2 + bl2)));
        float vu0 = __bfloat162float(Pd[512 + hd*192 + lane])
                  + __bfloat162float(Ps[1280 + hd*192 + lane])
                  + __bfloat162float(Ee[256 + hd*192 + lane]);
        float vu1 = __bfloat162float(Pd[512 + hd*192 + 64 + lane])
                  + __bfloat162float(Ps[1280 + hd*192 + 64 + lane])
                  + __bfloat162float(Ee[256 + hd*192 + 64 + lane]);
        float vu2 = __bfloat162float(Pd[512 + hd*192 + 128 + lane])
                  + __bfloat162float(Ps[1280 + hd*192 + 128 + lane])
                  + __bfloat162float(Ee[256 + hd*192 + 128 + lane]);
        sM[w][it][lane]       = g0*vu0;
        sM[w][it][64 + lane]  = g1*vu1;
        sM[w][it][128 + lane] = g2*vu2;
    }
    // wave-local LDS (same wave wrote it): compiler inserts lgkmcnt waits
    float acc0 = bms, acc1 = bms, acc2 = bms, acc3 = bms;
    #pragma unroll 8
    for (int k4 = 0; k4 < 48; ++k4) {
        float w0 = sW[(k4*4+0)*64 + lane], w1 = sW[(k4*4+1)*64 + lane];
        float w2 = sW[(k4*4+2)*64 + lane], w3 = sW[(k4*4+3)*64 + lane];
        float4 m0 = *(const float4*)&sM[w][0][k4*4];
        float4 m1 = *(const float4*)&sM[w][1][k4*4];
        float4 m2 = *(const float4*)&sM[w][2][k4*4];
        float4 m3 = *(const float4*)&sM[w][3][k4*4];
        acc0 += m0.x*w0 + m0.y*w1 + m0.z*w2 + m0.w*w3;
        acc1 += m1.x*w0 + m1.y*w1 + m1.z*w2 + m1.w*w3;
        acc2 += m2.x*w0 + m2.y*w1 + m2.z*w2 + m2.w*w3;
        acc3 += m3.x*w0 + m3.y*w1 + m3.z*w2 + m3.w*w3;
    }
    #pragma unroll
    for (int it = 0; it < 4; ++it) {
        float v = (it == 0) ? acc0 : (it == 1) ? acc1 : (it == 2) ? acc2 : acc3;
        float s = v, ss = v*v;
        #pragma unroll
        for (int m = 1; m < 64; m <<= 1) { s += __shfl_xor(s, m); ss += __shfl_xor(ss, m); }
        float mu = s * (1.f/64.f);
        float var = ss * (1.f/64.f) - mu*mu;
        float rstd = rsqrtf(var + EPSV);
        float mo = (v - mu)*rstd*gm + bm;
        atomicAdd(&agg[(size_t)dstv[it]*256 + hd*64 + lane], mo);
    }
}

// ---------------- out = agg@Wcat + bcat, with BN partial sums ----------------
__global__ __launch_bounds__(256, 2) void agg_out(
    const float* __restrict__ agg, const float* __restrict__ Wcat, const float* __restrict__ bcat,
    float* __restrict__ out, float* __restrict__ bnsum, float* __restrict__ bnss) {
    __shared__ float sW[256 * 64];
    __shared__ __align__(16) float sA[4][256];
    __shared__ float sR[4][64];
    int tid = threadIdx.x;
    for (int i = tid; i < 256*64; i += 256) sW[i] = Wcat[i];
    int c = tid & 63, no = tid >> 6;
    float bc = bcat[c];
    float psum = 0.f, psq = 0.f;
    __syncthreads();
    int nbase = blockIdx.x * 64;
    for (int it = 0; it < 16; ++it) {
        for (int i = tid; i < 1024; i += 256)
            sA[i >> 8][i & 255] = agg[(size_t)(nbase + it*4 + (i >> 8))*256 + (i & 255)];
        __syncthreads();
        float acc = bc;
        #pragma unroll
        for (int k4 = 0; k4 < 64; ++k4) {
            float4 av = *(const float4*)&sA[no][k4*4];
            acc += av.x*sW[(k4*4+0)*64 + c] + av.y*sW[(k4*4+1)*64 + c]
                 + av.z*sW[(k4*4+2)*64 + c] + av.w*sW[(k4*4+3)*64 + c];
        }
        out[(size_t)(nbase + it*4 + no)*64 + c] = acc;
        psum += acc; psq += acc*acc;
        __syncthreads();
    }
    sR[no][c] = psum; __syncthreads();
    if (no == 0) atomicAdd(&bnsum[c], sR[0][c] + sR[1][c] + sR[2][c] + sR[3][c]);
    __syncthreads();
    sR[no][c] = psq; __syncthreads();
    if (no == 0) atomicAdd(&bnss[c], sR[0][c] + sR[1][c] + sR[2][c] + sR[3][c]);
}

// ---------------- BN finalize + silu + residual ----------------
__global__ void bn_silu(const float* __restrict__ out, const float* __restrict__ HF,
                        const float* __restrict__ bnsum, const float* __restrict__ bnss,
                        const float* __restrict__ g_bn, const float* __restrict__ be_bn,
                        float* __restrict__ h) {
    int idx = blockIdx.x * 256 + threadIdx.x;   // N*64
    int c = idx & 63;
    float mu = bnsum[c] * (1.f/N_NODES);
    float var = bnss[c] * (1.f/N_NODES) - mu*mu;
    float rstd = rsqrtf(var + EPSV);
    float v = (out[idx] - mu)*rstd*g_bn[c] + be_bn[c];
    float sv = v / (1.f + __expf(-v));
    h[idx] = sv + HF[idx];
}

// ---------------- readout ----------------
__global__ void pool_sum(const float* __restrict__ h, const int* __restrict__ batch,
                         float* __restrict__ pooled) {
    int idx = blockIdx.x * 256 + threadIdx.x;
    int n = idx >> 6, c = idx & 63;
    atomicAdd(&pooled[batch[n]*64 + c], h[idx]);
}

__global__ void pool_cnt(const int* __restrict__ batch, float* __restrict__ cntf) {
    int n = blockIdx.x * 256 + threadIdx.x;
    if (n < N_NODES) atomicAdd(&cntf[batch[n]], 1.f);
}

__global__ void head_k(const float* __restrict__ pooled, const float* __restrict__ cntf,
                       const float* __restrict__ Wfc, const float* __restrict__ bfc,
                       const float* __restrict__ Wout, const float* __restrict__ bout,
                       float* __restrict__ d_out) {
    __shared__ float red[128];
    int g = blockIdx.x, t = threadIdx.x;
    float inv = 1.f / fmaxf(cntf[g], 1.f);
    float acc = bfc[t];
    #pragma unroll
    for (int k = 0; k < 64; ++k) acc += pooled[g*64 + k]*inv*Wfc[k*128 + t];
    float z = acc / (1.f + __expf(-acc));
    red[t] = z * Wout[t];
    __syncthreads();
    for (int s1 = 64; s1 > 0; s1 >>= 1) { if (t < s1) red[t] += red[t + s1]; __syncthreads(); }
    if (t == 0) d_out[g] = red[0] + bout[0];
}

// ---------------- launcher ----------------
extern "C" void kernel_launch(void* const* d_in, const int* in_sizes, int n_in,
                              void* d_out, int out_size, void* d_ws, size_t ws_size,
                              hipStream_t stream) {
    const float* x        = (const float*)d_in[0];
    const float* edge_attr= (const float*)d_in[1];
    const int*   ei       = (const int*)  d_in[2];
    const int*   batch    = (const int*)  d_in[3];
    const float* W_atom=(const float*)d_in[4];  const float* b_atom=(const float*)d_in[5];
    const float* We1  =(const float*)d_in[6];   const float* be1  =(const float*)d_in[7];
    const float* We2  =(const float*)d_in[8];   const float* be2  =(const float*)d_in[9];
    const float* Wq   =(const float*)d_in[10];  const float* bq   =(const float*)d_in[11];
    const float* Wk   =(const float*)d_in[12];  const float* bk   =(const float*)d_in[13];
    const float* Wv   =(const float*)d_in[14];  const float* bv   =(const float*)d_in[15];
    const float* Wedge=(const float*)d_in[16];  const float* bedge=(const float*)d_in[17];
    const float* Wfea =(const float*)d_in[18];  const float* bfea =(const float*)d_in[19];
    const float* Wcat =(const float*)d_in[20];  const float* bcat =(const float*)d_in[21];
    const float* Wupd =(const float*)d_in[22];  const float* bupd =(const float*)d_in[23];
    const float* Wmsg =(const float*)d_in[24];  const float* bmsg =(const float*)d_in[25];
    const float* g_msg=(const float*)d_in[26];  const float* be_msg=(const float*)d_in[27];
    const float* g_ln =(const float*)d_in[28];  const float* be_ln=(const float*)d_in[29];
    const float* g_bn =(const float*)d_in[30];  const float* be_bn=(const float*)d_in[31];
    const float* Wfc  =(const float*)d_in[32];  const float* bfc  =(const float*)d_in[33];
    const float* Wout =(const float*)d_in[34];  const float* bout =(const float*)d_in[35];

    char* ws = (char*)d_ws;
    size_t off = 0;
    auto alloc = [&](size_t bytes) {
        void* p = ws + off;
        off += (bytes + 255) & ~(size_t)255;
        return p;
    };
    float* Wnp  = (float*)alloc((size_t)NL*64*PC*4);
    float* bnp  = (float*)alloc((size_t)NL*PC*4);
    float* Wep  = (float*)alloc((size_t)NL*64*ECOLS*4);
    float* bep  = (float*)alloc((size_t)NL*ECOLS*4);
    float* h    = (float*)alloc((size_t)N_NODES*64*4);
    float* ef   = (float*)alloc((size_t)N_EDGES*64*4);
    bf16*  P    = (bf16*) alloc((size_t)N_NODES*PC*2);
    float* HF   = (float*)alloc((size_t)N_NODES*64*4);
    float* agg  = (float*)alloc((size_t)N_NODES*256*4);
    float* bnsum= (float*)alloc(64*4);
    float* bnss = (float*)alloc(64*4);
    float* pooled=(float*)alloc(64*64*4);
    float* cntf = (float*)alloc(64*4);
    // EP gets the remainder; pick largest chunk that fits
    int EC = 0;
    const int cand[5] = {64000, 32000, 16000, 8000, 4000};
    for (int i = 0; i < 5; ++i) {
        size_t need = (size_t)cand[i]*ECOLS*2;
        if (off + need <= ws_size) { EC = cand[i]; break; }
    }
    if (EC == 0) return;  // workspace too small — fail visibly
    bf16* EP = (bf16*)alloc((size_t)EC*ECOLS*2);
    float* outb = (float*)EP;  // alias: EP is dead when agg_out runs; rewritten next layer after bn_silu
    int NCHUNK = N_EDGES / EC;

    {
        int total = NL*64*(PC+ECOLS);
        pack_w<<<(total+255)/256, 256, 0, stream>>>(Wq, Wk, Wv, Wupd, Wedge, Wnp, Wep);
        int tb = NL*(PC+ECOLS);
        pack_b<<<(tb+255)/256, 256, 0, stream>>>(bq, bk, bv, Wupd, bupd, bedge, bnp, bep);
    }
    init_h<<<(N_NODES*64)/256, 256, 0, stream>>>(x, W_atom, b_atom, h);
    init_e<<<N_EDGES/4, 256, 0, stream>>>(edge_attr, We1, be1, We2, be2, ef);

    for (int l = 0; l < NL; ++l) {
        proj_gemm<<<dim3(PC/256, 500), 256, 0, stream>>>(
            h, Wnp + (size_t)l*64*PC, bnp + l*PC, P, N_NODES, PC);
        hf_proj<<<N_NODES/4, 256, 0, stream>>>(h, Wfea + (size_t)l*64*64, bfea + l*64, HF);
        hipMemsetAsync(agg, 0, (size_t)N_NODES*256*4, stream);
        hipMemsetAsync(bnsum, 0, 64*4, stream);
        hipMemsetAsync(bnss, 0, 64*4, stream);
        for (int ch = 0; ch < NCHUNK; ++ch) {
            proj_gemm<<<dim3(ECOLS/256, 500), 256, 0, stream>>>(
                ef + (size_t)ch*EC*64, Wep + (size_t)l*64*ECOLS, bep + l*ECOLS, EP, EC, ECOLS);
            edge_fused<<<EC/8, 512, 0, stream>>>(
                P, EP, ei, ch*EC, Wmsg + (size_t)l*192*64, bmsg + l*64,
                g_ln + l*192, be_ln + l*192, g_msg + l*64, be_msg + l*64, agg);
        }
        agg_out<<<N_NODES/64, 256, 0, stream>>>(agg, Wcat + (size_t)l*256*64, bcat + l*64,
                                                outb, bnsum, bnss);
        bn_silu<<<(N_NODES*64)/256, 256, 0, stream>>>(outb, HF, bnsum, bnss,
                                                      g_bn + l*64, be_bn + l*64, h);
    }
    hipMemsetAsync(pooled, 0, 64*64*4, stream);
    hipMemsetAsync(cntf, 0, 64*4, stream);
    pool_sum<<<(N_NODES*64)/256, 256, 0, stream>>>(h, batch, pooled);
    pool_cnt<<<(N_NODES+255)/256, 256, 0, stream>>>(batch, cntf);
    head_k<<<N_GRAPH, 128, 0, stream>>>(pooled, cntf, Wfc, bfc, Wout, bout, (float*)d_out);
}

// Round 3
// 3373.400 us; speedup vs baseline: 1.8518x; 1.8518x over previous
//
#include <hip/hip_runtime.h>
#include <hip/hip_bf16.h>
#include <math.h>

#define N_NODES 16000
#define N_EDGES 128000
#define N_GRAPH 64
#define NL 5
#define EPSV 1e-5f
#define SCALE 0.07216878364870323f   // 1/sqrt(192)

#define PC 2048      // P cols (bf16): [0,256)=Q | [256,512)=K | [512,1280)=VdT | [1280,2048)=VsT
#define ECOLS 1024   // EP cols (bf16): [0,256)=Eh | [256,1024)=EhT (bupd folded into bias)

typedef __hip_bfloat16 bf16;
typedef __attribute__((ext_vector_type(8))) short short8;
typedef __attribute__((ext_vector_type(4))) float f32x4;

__device__ __forceinline__ ushort f2b(float x) {
    union { float f; uint u; } v; v.f = x;
    uint r = v.u + 0x7fffu + ((v.u >> 16) & 1u);   // RNE
    return (ushort)(r >> 16);
}
__device__ __forceinline__ float b2f_lo(uint u) { union { uint u; float f; } v; v.u = u << 16; return v.f; }
__device__ __forceinline__ float b2f_hi(uint u) { union { uint u; float f; } v; v.u = u & 0xffff0000u; return v.f; }

// ---------------- weight packing (bf16, MFMA B-fragment order) ----------------
// Fragment order for W[64,M], per layer: tile t=col/16, kstep s=k/32,
// lane = (col&15) | (((k&31)>>3)<<4), j = k&7  ->  flat ((t*2+s)*64+lane)*8+j
__global__ void pack_w(const float* __restrict__ Wq, const float* __restrict__ Wk,
                       const float* __restrict__ Wv, const float* __restrict__ Wupd,
                       const float* __restrict__ Wedge,
                       short* __restrict__ Wnp, short* __restrict__ Wep) {
    int idx = blockIdx.x * 256 + threadIdx.x;
    int total = NL * 64 * (PC + ECOLS);
    if (idx >= total) return;
    int c = idx % (PC + ECOLS);
    int k = (idx / (PC + ECOLS)) % 64;
    int l = idx / (64 * (PC + ECOLS));
    if (c < PC) {
        float v = 0.f;
        if (c < 256) v = Wq[(l*64 + k)*256 + c];
        else if (c < 512) v = Wk[(l*64 + k)*256 + (c - 256)];
        else if (c < 1280) {
            int cc = c - 512, hd = cc / 192, p = cc % 192;
            float s = 0.f;
            for (int q = 0; q < 64; ++q)
                s += Wv[(l*64 + k)*256 + hd*64 + q] * Wupd[(l*192 + q)*192 + p];
            v = s;
        } else {
            int cc = c - 1280, hd = cc / 192, p = cc % 192;
            float s = 0.f;
            for (int q = 0; q < 64; ++q)
                s += Wv[(l*64 + k)*256 + hd*64 + q] * Wupd[(l*192 + 64 + q)*192 + p];
            v = s;
        }
        int t = c >> 4, s = k >> 5, lane = (c & 15) | (((k & 31) >> 3) << 4), jj = k & 7;
        Wnp[(size_t)l*64*PC + ((size_t)(t*2 + s)*64 + lane)*8 + jj] = (short)f2b(v);
    } else {
        int ce = c - PC;
        float v;
        if (ce < 256) v = Wedge[(l*64 + k)*256 + ce];
        else {
            int cc = ce - 256, hd = cc / 192, p = cc % 192;
            float s = 0.f;
            for (int q = 0; q < 64; ++q)
                s += Wedge[(l*64 + k)*256 + hd*64 + q] * Wupd[(l*192 + 128 + q)*192 + p];
            v = s;
        }
        int t = ce >> 4, s = k >> 5, lane = (ce & 15) | (((k & 31) >> 3) << 4), jj = k & 7;
        Wep[(size_t)l*64*ECOLS + ((size_t)(t*2 + s)*64 + lane)*8 + jj] = (short)f2b(v);
    }
}

__global__ void pack_b(const float* __restrict__ bq, const float* __restrict__ bk,
                       const float* __restrict__ bv, const float* __restrict__ Wupd,
                       const float* __restrict__ bupd, const float* __restrict__ bedge,
                       float* __restrict__ bnp, float* __restrict__ bep) {
    int idx = blockIdx.x * 256 + threadIdx.x;
    int total = NL * (PC + ECOLS);
    if (idx >= total) return;
    int c = idx % (PC + ECOLS);
    int l = idx / (PC + ECOLS);
    if (c < PC) {
        float v = 0.f;
        if (c < 256) v = bq[l*256 + c];
        else if (c < 512) v = bk[l*256 + c - 256];
        else if (c < 1280) {
            int cc = c - 512, hd = cc / 192, p = cc % 192;
            float s = 0.f;
            for (int k = 0; k < 64; ++k) s += bv[l*256 + hd*64 + k] * Wupd[(l*192 + k)*192 + p];
            v = s;
        } else {
            int cc = c - 1280, hd = cc / 192, p = cc % 192;
            float s = 0.f;
            for (int k = 0; k < 64; ++k) s += bv[l*256 + hd*64 + k] * Wupd[(l*192 + 64 + k)*192 + p];
            v = s;
        }
        bnp[l*PC + c] = v;
    } else {
        int ce = c - PC;
        float v;
        if (ce < 256) v = bedge[l*256 + ce];
        else {
            int cc = ce - 256, hd = cc / 192, p = cc % 192;
            float s = bupd[l*192 + p];  // fold bupd here
            for (int k = 0; k < 64; ++k) s += bedge[l*256 + hd*64 + k] * Wupd[(l*192 + 128 + k)*192 + p];
            v = s;
        }
        bep[l*ECOLS + ce] = v;
    }
}

// ---------------- initial embeddings ----------------
__global__ void init_h(const float* __restrict__ x, const float* __restrict__ W_atom,
                       const float* __restrict__ b_atom, float* __restrict__ h) {
    int idx = blockIdx.x * 256 + threadIdx.x;   // N*64
    int d = idx & 63, n = idx >> 6;
    float s = b_atom[d];
    #pragma unroll
    for (int j = 0; j < 4; ++j) s += x[n*4 + j] * W_atom[j*64 + d];
    h[idx] = s;
}

__global__ void init_e(const float* __restrict__ ea, const float* __restrict__ We1,
                       const float* __restrict__ be1, const float* __restrict__ We2,
                       const float* __restrict__ be2, float* __restrict__ ef) {
    __shared__ float sT[4][64];
    int tid = threadIdx.x, d = tid & 63, sub = tid >> 6;
    int e = blockIdx.x * 4 + sub;
    float s = be1[d];
    #pragma unroll
    for (int j = 0; j < 9; ++j) s += ea[e*9 + j] * We1[j*64 + d];
    float x64 = s * 64.f;
    float sp = (x64 > 64.f) ? s : log1pf(__expf(fminf(x64, 64.f))) * (1.f/64.f);
    sT[sub][d] = sp;   // wave-local
    float acc = be2[d];
    #pragma unroll
    for (int k = 0; k < 64; ++k) acc += sT[sub][k] * We2[k*64 + d];
    ef[(size_t)e*64 + d] = acc;
}

// ---------------- MFMA projection: out_bf16[rows,M] = A_f32[rows,64] @ Wpk + bias ----------------
// block: 256 thr (4 waves); tile 16 rows x 256 cols; each wave: 4 n-tiles x (K=64 -> 2 ksteps)
#define CPAD 260
__global__ __launch_bounds__(256, 8) void proj_mfma(
    const float* __restrict__ A, const short* __restrict__ Wpk, const float* __restrict__ bias,
    ushort* __restrict__ out, int M) {
    __shared__ short aFrag[2*64*8];       // 2 KB, A-fragment order
    __shared__ ushort cTile[16*CPAD];     // epilogue bounce
    int tid = threadIdx.x;
    int row0 = blockIdx.y * 16;
    int col0 = blockIdx.x * 256;
    {   // stage A: contiguous 4KB global read, scatter to fragment order
        int r = tid >> 4, k0 = (tid & 15) * 4;
        const float4 v = *(const float4*)(A + (size_t)(row0 + r)*64 + k0);
        int s = k0 >> 5, lane = r | (((k0 & 31) >> 3) << 4), j0 = k0 & 7;
        ushort4 b; b.x = f2b(v.x); b.y = f2b(v.y); b.z = f2b(v.z); b.w = f2b(v.w);
        *(ushort4*)&aFrag[(s*64 + lane)*8 + j0] = b;
    }
    __syncthreads();
    int w = tid >> 6, lane = tid & 63;
    short8 a0 = *(const short8*)&aFrag[(0*64 + lane)*8];
    short8 a1 = *(const short8*)&aFrag[(1*64 + lane)*8];
    int cl = lane & 15, rg = lane >> 4;
    #pragma unroll
    for (int nt = 0; nt < 4; ++nt) {
        int t = (col0 >> 4) + w*4 + nt;
        const short* bp = Wpk + ((size_t)(t*2)*64 + lane)*8;
        short8 b0 = *(const short8*)bp;
        short8 b1 = *(const short8*)(bp + 64*8);
        f32x4 acc = {0.f, 0.f, 0.f, 0.f};
        acc = __builtin_amdgcn_mfma_f32_16x16x32_bf16(a0, b0, acc, 0, 0, 0);
        acc = __builtin_amdgcn_mfma_f32_16x16x32_bf16(a1, b1, acc, 0, 0, 0);
        int ccol = w*64 + nt*16 + cl;
        float bv = bias[col0 + ccol];
        #pragma unroll
        for (int r = 0; r < 4; ++r)
            cTile[(rg*4 + r)*CPAD + ccol] = f2b(acc[r] + bv);
    }
    __syncthreads();
    {   // copy out: 512B-contiguous per 16 threads
        int r = tid >> 4, cs = (tid & 15) * 16;
        ushort* dst = out + (size_t)(row0 + r)*M + col0 + cs;
        const ushort* srcp = &cTile[r*CPAD + cs];
        #pragma unroll
        for (int q = 0; q < 4; ++q)
            *(ushort4*)(dst + q*4) = *(const ushort4*)(srcp + q*4);
    }
}

// ---------------- HF = h @ Wfea + bfea (f32, residual path) ----------------
__global__ __launch_bounds__(256) void hf_proj(const float* __restrict__ h,
                                               const float* __restrict__ Wfea,
                                               const float* __restrict__ bfea,
                                               float* __restrict__ HF) {
    __shared__ float sW[64*64];
    __shared__ __align__(16) float sA[4][64];
    int tid = threadIdx.x;
    for (int i = tid; i < 4096; i += 256) sW[i] = Wfea[i];
    int c = tid & 63, no = tid >> 6;
    int n0 = blockIdx.x * 4;
    sA[no][c] = h[(size_t)(n0 + no)*64 + c];
    __syncthreads();
    float acc = bfea[c];
    #pragma unroll
    for (int k4 = 0; k4 < 16; ++k4) {
        float4 av = *(const float4*)&sA[no][k4*4];
        acc += av.x*sW[(k4*4+0)*64+c] + av.y*sW[(k4*4+1)*64+c]
             + av.z*sW[(k4*4+2)*64+c] + av.w*sW[(k4*4+3)*64+c];
    }
    HF[(size_t)(n0 + no)*64 + c] = acc;
}

// ---------------- fused per-edge attention/gating/message ----------------
__global__ __launch_bounds__(512, 6) void edge_fused(
    const bf16* __restrict__ P, const bf16* __restrict__ EP,
    const int* __restrict__ ei, int chunk_base,
    const float* __restrict__ Wmsg, const float* __restrict__ bmsg,
    const float* __restrict__ g_ln, const float* __restrict__ be_ln,
    const float* __restrict__ g_msg, const float* __restrict__ be_msg,
    float* __restrict__ agg) {
    __shared__ uint sWp[96*64];                    // 24 KB: Wmsg bf16 pairs (k=2p,2p+1)
    __shared__ __align__(16) float sM[8][4][192];  // 24 KB
    int tid = threadIdx.x;
    for (int i = tid; i < 96*64; i += 512) {
        int p = i >> 6, col = i & 63;
        sWp[i] = (uint)f2b(Wmsg[(2*p)*64 + col]) | ((uint)f2b(Wmsg[(2*p + 1)*64 + col]) << 16);
    }
    int lane = tid & 63, w = tid >> 6, hd = w & 3;
    float gl0 = g_ln[lane], gl1 = g_ln[64 + lane], gl2 = g_ln[128 + lane];
    float bl0 = be_ln[lane], bl1 = be_ln[64 + lane], bl2 = be_ln[128 + lane];
    float gm = g_msg[lane], bm = be_msg[lane], bms = bmsg[lane];
    __syncthreads();
    int e0 = blockIdx.x * 8 + (w >> 2) * 4;   // this wave: 4 edges, head hd
    int dstv[4];
    #pragma unroll
    for (int it = 0; it < 4; ++it) {
        int el = e0 + it, eg = chunk_base + el;
        int src = ei[eg], dst = ei[N_EDGES + eg];
        dstv[it] = dst;
        const bf16* Pd = P + (size_t)dst * PC;
        const bf16* Ps = P + (size_t)src * PC;
        const bf16* Ee = EP + (size_t)el * ECOLS;
        float q  = __bfloat162float(Pd[hd*64 + lane]);
        float kd = __bfloat162float(Pd[256 + hd*64 + lane]);
        float ks = __bfloat162float(Ps[256 + hd*64 + lane]);
        float eh = __bfloat162float(Ee[hd*64 + lane]);
        float a0 = q*kd*SCALE, a1 = q*ks*SCALE, a2 = q*eh*SCALE;
        float s = a0 + a1 + a2, ss = a0*a0 + a1*a1 + a2*a2;
        #pragma unroll
        for (int m = 1; m < 64; m <<= 1) { s += __shfl_xor(s, m); ss += __shfl_xor(ss, m); }
        float mu = s * (1.f/192.f);
        float var = ss * (1.f/192.f) - mu*mu;
        float rstd = rsqrtf(var + EPSV);
        float g0 = 1.f/(1.f + __expf(-((a0 - mu)*rstd*gl0 + bl0)));
        float g1 = 1.f/(1.f + __expf(-((a1 - mu)*rstd*gl1 + bl1)));
        float g2 = 1.f/(1.f + __expf(-((a2 - mu)*rstd*gl2 + bl2)));
        float vu0 = __bfloat162float(Pd[512 + hd*192 + lane])
                  + __bfloat162float(Ps[1280 + hd*192 + lane])
                  + __bfloat162float(Ee[256 + hd*192 + lane]);
        float vu1 = __bfloat162float(Pd[512 + hd*192 + 64 + lane])
                  + __bfloat162float(Ps[1280 + hd*192 + 64 + lane])
                  + __bfloat162float(Ee[256 + hd*192 + 64 + lane]);
        float vu2 = __bfloat162float(Pd[512 + hd*192 + 128 + lane])
                  + __bfloat162float(Ps[1280 + hd*192 + 128 + lane])
                  + __bfloat162float(Ee[256 + hd*192 + 128 + lane]);
        sM[w][it][lane]       = g0*vu0;
        sM[w][it][64 + lane]  = g1*vu1;
        sM[w][it][128 + lane] = g2*vu2;
    }
    float acc0 = bms, acc1 = bms, acc2 = bms, acc3 = bms;
    #pragma unroll 8
    for (int k4 = 0; k4 < 48; ++k4) {
        uint u0 = sWp[(k4*2 + 0)*64 + lane];
        uint u1 = sWp[(k4*2 + 1)*64 + lane];
        float w0 = b2f_lo(u0), w1 = b2f_hi(u0);
        float w2 = b2f_lo(u1), w3 = b2f_hi(u1);
        float4 m0 = *(const float4*)&sM[w][0][k4*4];
        float4 m1 = *(const float4*)&sM[w][1][k4*4];
        float4 m2 = *(const float4*)&sM[w][2][k4*4];
        float4 m3 = *(const float4*)&sM[w][3][k4*4];
        acc0 += m0.x*w0 + m0.y*w1 + m0.z*w2 + m0.w*w3;
        acc1 += m1.x*w0 + m1.y*w1 + m1.z*w2 + m1.w*w3;
        acc2 += m2.x*w0 + m2.y*w1 + m2.z*w2 + m2.w*w3;
        acc3 += m3.x*w0 + m3.y*w1 + m3.z*w2 + m3.w*w3;
    }
    #pragma unroll
    for (int it = 0; it < 4; ++it) {
        float v = (it == 0) ? acc0 : (it == 1) ? acc1 : (it == 2) ? acc2 : acc3;
        float s = v, ss = v*v;
        #pragma unroll
        for (int m = 1; m < 64; m <<= 1) { s += __shfl_xor(s, m); ss += __shfl_xor(ss, m); }
        float mu = s * (1.f/64.f);
        float var = ss * (1.f/64.f) - mu*mu;
        float rstd = rsqrtf(var + EPSV);
        float mo = (v - mu)*rstd*gm + bm;
        atomicAdd(&agg[(size_t)dstv[it]*256 + hd*64 + lane], mo);
    }
}

// ---------------- out = agg@Wcat + bcat, with BN partial sums ----------------
__global__ __launch_bounds__(256, 2) void agg_out(
    const float* __restrict__ agg, const float* __restrict__ Wcat, const float* __restrict__ bcat,
    float* __restrict__ out, float* __restrict__ bnsum, float* __restrict__ bnss) {
    __shared__ float sW[256 * 64];
    __shared__ __align__(16) float sA[4][256];
    __shared__ float sR[4][64];
    int tid = threadIdx.x;
    for (int i = tid; i < 256*64; i += 256) sW[i] = Wcat[i];
    int c = tid & 63, no = tid >> 6;
    float bc = bcat[c];
    float psum = 0.f, psq = 0.f;
    __syncthreads();
    int nbase = blockIdx.x * 64;
    for (int it = 0; it < 16; ++it) {
        for (int i = tid; i < 1024; i += 256)
            sA[i >> 8][i & 255] = agg[(size_t)(nbase + it*4 + (i >> 8))*256 + (i & 255)];
        __syncthreads();
        float acc = bc;
        #pragma unroll
        for (int k4 = 0; k4 < 64; ++k4) {
            float4 av = *(const float4*)&sA[no][k4*4];
            acc += av.x*sW[(k4*4+0)*64 + c] + av.y*sW[(k4*4+1)*64 + c]
                 + av.z*sW[(k4*4+2)*64 + c] + av.w*sW[(k4*4+3)*64 + c];
        }
        out[(size_t)(nbase + it*4 + no)*64 + c] = acc;
        psum += acc; psq += acc*acc;
        __syncthreads();
    }
    sR[no][c] = psum; __syncthreads();
    if (no == 0) atomicAdd(&bnsum[c], sR[0][c] + sR[1][c] + sR[2][c] + sR[3][c]);
    __syncthreads();
    sR[no][c] = psq; __syncthreads();
    if (no == 0) atomicAdd(&bnss[c], sR[0][c] + sR[1][c] + sR[2][c] + sR[3][c]);
}

// ---------------- BN finalize + silu + residual ----------------
__global__ void bn_silu(const float* __restrict__ out, const float* __restrict__ HF,
                        const float* __restrict__ bnsum, const float* __restrict__ bnss,
                        const float* __restrict__ g_bn, const float* __restrict__ be_bn,
                        float* __restrict__ h) {
    int idx = blockIdx.x * 256 + threadIdx.x;   // N*64
    int c = idx & 63;
    float mu = bnsum[c] * (1.f/N_NODES);
    float var = bnss[c] * (1.f/N_NODES) - mu*mu;
    float rstd = rsqrtf(var + EPSV);
    float v = (out[idx] - mu)*rstd*g_bn[c] + be_bn[c];
    float sv = v / (1.f + __expf(-v));
    h[idx] = sv + HF[idx];
}

// ---------------- readout ----------------
__global__ void pool_sum(const float* __restrict__ h, const int* __restrict__ batch,
                         float* __restrict__ pooled) {
    int idx = blockIdx.x * 256 + threadIdx.x;
    int n = idx >> 6, c = idx & 63;
    atomicAdd(&pooled[batch[n]*64 + c], h[idx]);
}

__global__ void pool_cnt(const int* __restrict__ batch, float* __restrict__ cntf) {
    int n = blockIdx.x * 256 + threadIdx.x;
    if (n < N_NODES) atomicAdd(&cntf[batch[n]], 1.f);
}

__global__ void head_k(const float* __restrict__ pooled, const float* __restrict__ cntf,
                       const float* __restrict__ Wfc, const float* __restrict__ bfc,
                       const float* __restrict__ Wout, const float* __restrict__ bout,
                       float* __restrict__ d_out) {
    __shared__ float red[128];
    int g = blockIdx.x, t = threadIdx.x;
    float inv = 1.f / fmaxf(cntf[g], 1.f);
    float acc = bfc[t];
    #pragma unroll
    for (int k = 0; k < 64; ++k) acc += pooled[g*64 + k]*inv*Wfc[k*128 + t];
    float z = acc / (1.f + __expf(-acc));
    red[t] = z * Wout[t];
    __syncthreads();
    for (int s1 = 64; s1 > 0; s1 >>= 1) { if (t < s1) red[t] += red[t + s1]; __syncthreads(); }
    if (t == 0) d_out[g] = red[0] + bout[0];
}

// ---------------- launcher ----------------
extern "C" void kernel_launch(void* const* d_in, const int* in_sizes, int n_in,
                              void* d_out, int out_size, void* d_ws, size_t ws_size,
                              hipStream_t stream) {
    const float* x        = (const float*)d_in[0];
    const float* edge_attr= (const float*)d_in[1];
    const int*   ei       = (const int*)  d_in[2];
    const int*   batch    = (const int*)  d_in[3];
    const float* W_atom=(const float*)d_in[4];  const float* b_atom=(const float*)d_in[5];
    const float* We1  =(const float*)d_in[6];   const float* be1  =(const float*)d_in[7];
    const float* We2  =(const float*)d_in[8];   const float* be2  =(const float*)d_in[9];
    const float* Wq   =(const float*)d_in[10];  const float* bq   =(const float*)d_in[11];
    const float* Wk   =(const float*)d_in[12];  const float* bk   =(const float*)d_in[13];
    const float* Wv   =(const float*)d_in[14];  const float* bv   =(const float*)d_in[15];
    const float* Wedge=(const float*)d_in[16];  const float* bedge=(const float*)d_in[17];
    const float* Wfea =(const float*)d_in[18];  const float* bfea =(const float*)d_in[19];
    const float* Wcat =(const float*)d_in[20];  const float* bcat =(const float*)d_in[21];
    const float* Wupd =(const float*)d_in[22];  const float* bupd =(const float*)d_in[23];
    const float* Wmsg =(const float*)d_in[24];  const float* bmsg =(const float*)d_in[25];
    const float* g_msg=(const float*)d_in[26];  const float* be_msg=(const float*)d_in[27];
    const float* g_ln =(const float*)d_in[28];  const float* be_ln=(const float*)d_in[29];
    const float* g_bn =(const float*)d_in[30];  const float* be_bn=(const float*)d_in[31];
    const float* Wfc  =(const float*)d_in[32];  const float* bfc  =(const float*)d_in[33];
    const float* Wout =(const float*)d_in[34];  const float* bout =(const float*)d_in[35];

    char* ws = (char*)d_ws;
    size_t off = 0;
    auto alloc = [&](size_t bytes) {
        void* p = ws + off;
        off += (bytes + 255) & ~(size_t)255;
        return p;
    };
    short* Wnp  = (short*)alloc((size_t)NL*64*PC*2);
    float* bnp  = (float*)alloc((size_t)NL*PC*4);
    short* Wep  = (short*)alloc((size_t)NL*64*ECOLS*2);
    float* bep  = (float*)alloc((size_t)NL*ECOLS*4);
    float* h    = (float*)alloc((size_t)N_NODES*64*4);
    float* ef   = (float*)alloc((size_t)N_EDGES*64*4);
    bf16*  P    = (bf16*) alloc((size_t)N_NODES*PC*2);
    float* HF   = (float*)alloc((size_t)N_NODES*64*4);
    float* agg  = (float*)alloc((size_t)N_NODES*256*4);
    float* bnsum= (float*)alloc(64*4);
    float* bnss = (float*)alloc(64*4);
    float* pooled=(float*)alloc(64*64*4);
    float* cntf = (float*)alloc(64*4);
    int EC = 0;
    const int cand[5] = {64000, 32000, 16000, 8000, 4000};
    for (int i = 0; i < 5; ++i) {
        size_t need = (size_t)cand[i]*ECOLS*2;
        if (off + need <= ws_size) { EC = cand[i]; break; }
    }
    if (EC == 0) return;  // workspace too small — fail visibly
    bf16* EP = (bf16*)alloc((size_t)EC*ECOLS*2);
    float* outb = (float*)EP;  // alias: EP dead when agg_out runs
    int NCHUNK = N_EDGES / EC;

    {
        int total = NL*64*(PC+ECOLS);
        pack_w<<<(total+255)/256, 256, 0, stream>>>(Wq, Wk, Wv, Wupd, Wedge, Wnp, Wep);
        int tb = NL*(PC+ECOLS);
        pack_b<<<(tb+255)/256, 256, 0, stream>>>(bq, bk, bv, Wupd, bupd, bedge, bnp, bep);
    }
    init_h<<<(N_NODES*64)/256, 256, 0, stream>>>(x, W_atom, b_atom, h);
    init_e<<<N_EDGES/4, 256, 0, stream>>>(edge_attr, We1, be1, We2, be2, ef);

    for (int l = 0; l < NL; ++l) {
        proj_mfma<<<dim3(PC/256, N_NODES/16), 256, 0, stream>>>(
            h, Wnp + (size_t)l*64*PC, bnp + l*PC, (ushort*)P, PC);
        hf_proj<<<N_NODES/4, 256, 0, stream>>>(h, Wfea + (size_t)l*64*64, bfea + l*64, HF);
        hipMemsetAsync(agg, 0, (size_t)N_NODES*256*4, stream);
        hipMemsetAsync(bnsum, 0, 64*4, stream);
        hipMemsetAsync(bnss, 0, 64*4, stream);
        for (int ch = 0; ch < NCHUNK; ++ch) {
            proj_mfma<<<dim3(ECOLS/256, EC/16), 256, 0, stream>>>(
                ef + (size_t)ch*EC*64, Wep + (size_t)l*64*ECOLS, bep + l*ECOLS, (ushort*)EP, ECOLS);
            edge_fused<<<EC/8, 512, 0, stream>>>(
                P, EP, ei, ch*EC, Wmsg + (size_t)l*192*64, bmsg + l*64,
                g_ln + l*192, be_ln + l*192, g_msg + l*64, be_msg + l*64, agg);
        }
        agg_out<<<N_NODES/64, 256, 0, stream>>>(agg, Wcat + (size_t)l*256*64, bcat + l*64,
                                                outb, bnsum, bnss);
        bn_silu<<<(N_NODES*64)/256, 256, 0, stream>>>(outb, HF, bnsum, bnss,
                                                      g_bn + l*64, be_bn + l*64, h);
    }
    hipMemsetAsync(pooled, 0, 64*64*4, stream);
    hipMemsetAsync(cntf, 0, 64*4, stream);
    pool_sum<<<(N_NODES*64)/256, 256, 0, stream>>>(h, batch, pooled);
    pool_cnt<<<(N_NODES+255)/256, 256, 0, stream>>>(batch, cntf);
    head_k<<<N_GRAPH, 128, 0, stream>>>(pooled, cntf, Wfc, bfc, Wout, bout, (float*)d_out);
}

// Round 4
// 2192.618 us; speedup vs baseline: 2.8490x; 1.5385x over previous
//
#include <hip/hip_runtime.h>
#include <hip/hip_bf16.h>
#include <math.h>

#define N_NODES 16000
#define N_EDGES 128000
#define N_GRAPH 64
#define NL 5
#define EPSV 1e-5f
#define SCALE 0.07216878364870323f   // 1/sqrt(192)

#define PC 2048      // P cols (bf16): [0,256)=Q | [256,512)=K | [512,1280)=VdT | [1280,2048)=VsT
#define ECOLS 1024   // EP cols (bf16): [0,256)=Eh | [256,1024)=EhT (bupd folded into bias)
#define TILE 16      // edges per block in edge_fused
#define KPAD 196     // padded K-dim for m tile in LDS (bank-stride 2)

typedef __hip_bfloat16 bf16;
typedef __attribute__((ext_vector_type(8))) short short8;
typedef __attribute__((ext_vector_type(4))) short s4v;
typedef __attribute__((ext_vector_type(4))) float f32x4;
union S8U { short8 v; s4v h[2]; };

__device__ __forceinline__ ushort f2b(float x) {
    union { float f; uint u; } v; v.f = x;
    uint r = v.u + 0x7fffu + ((v.u >> 16) & 1u);   // RNE
    return (ushort)(r >> 16);
}
__device__ __forceinline__ float b2fu(ushort u) { union { uint u; float f; } v; v.u = (uint)u << 16; return v.f; }

// ---------------- weight packing (hi/lo bf16, MFMA B-fragment order) ----------------
// frag offset for W[64,M]: t=col/16, s=k/32, lane=(col&15)|(((k&31)>>3)<<4), j=k&7
__global__ void pack_w(const float* __restrict__ Wq, const float* __restrict__ Wk,
                       const float* __restrict__ Wv, const float* __restrict__ Wupd,
                       const float* __restrict__ Wedge,
                       short* __restrict__ Wnp, short* __restrict__ Wep) {
    int idx = blockIdx.x * 256 + threadIdx.x;
    int total = NL * 64 * (PC + ECOLS);
    if (idx >= total) return;
    int c = idx % (PC + ECOLS);
    int k = (idx / (PC + ECOLS)) % 64;
    int l = idx / (64 * (PC + ECOLS));
    if (c < PC) {
        float v = 0.f;
        if (c < 256) v = Wq[(l*64 + k)*256 + c];
        else if (c < 512) v = Wk[(l*64 + k)*256 + (c - 256)];
        else if (c < 1280) {
            int cc = c - 512, hd = cc / 192, p = cc % 192;
            float s = 0.f;
            for (int q = 0; q < 64; ++q)
                s += Wv[(l*64 + k)*256 + hd*64 + q] * Wupd[(l*192 + q)*192 + p];
            v = s;
        } else {
            int cc = c - 1280, hd = cc / 192, p = cc % 192;
            float s = 0.f;
            for (int q = 0; q < 64; ++q)
                s += Wv[(l*64 + k)*256 + hd*64 + q] * Wupd[(l*192 + 64 + q)*192 + p];
            v = s;
        }
        int t = c >> 4, s = k >> 5, lane = (c & 15) | (((k & 31) >> 3) << 4), jj = k & 7;
        size_t fo = ((size_t)(t*2 + s)*64 + lane)*8 + jj;
        ushort hi = f2b(v);
        ushort lo = f2b(v - b2fu(hi));
        Wnp[(size_t)l*2*64*PC + fo] = (short)hi;
        Wnp[(size_t)l*2*64*PC + (size_t)64*PC + fo] = (short)lo;
    } else {
        int ce = c - PC;
        float v;
        if (ce < 256) v = Wedge[(l*64 + k)*256 + ce];
        else {
            int cc = ce - 256, hd = cc / 192, p = cc % 192;
            float s = 0.f;
            for (int q = 0; q < 64; ++q)
                s += Wedge[(l*64 + k)*256 + hd*64 + q] * Wupd[(l*192 + 128 + q)*192 + p];
            v = s;
        }
        int t = ce >> 4, s = k >> 5, lane = (ce & 15) | (((k & 31) >> 3) << 4), jj = k & 7;
        size_t fo = ((size_t)(t*2 + s)*64 + lane)*8 + jj;
        ushort hi = f2b(v);
        ushort lo = f2b(v - b2fu(hi));
        Wep[(size_t)l*2*64*ECOLS + fo] = (short)hi;
        Wep[(size_t)l*2*64*ECOLS + (size_t)64*ECOLS + fo] = (short)lo;
    }
}

// Wmsg [192,64] per layer -> bf16 B-fragments: tile index (t*6+s), 24 tiles/layer
__global__ void pack_wmsg(const float* __restrict__ Wmsg, short* __restrict__ Wmf) {
    int idx = blockIdx.x * 256 + threadIdx.x;
    if (idx >= NL*192*64) return;
    int col = idx & 63, k = (idx >> 6) % 192, l = idx / (192*64);
    float v = Wmsg[(size_t)(l*192 + k)*64 + col];
    int t = col >> 4, s = k >> 5, lane = (col & 15) | (((k & 31) >> 3) << 4), j = k & 7;
    Wmf[(size_t)l*12288 + ((size_t)((t*6 + s)*64) + lane)*8 + j] = (short)f2b(v);
}

__global__ void pack_b(const float* __restrict__ bq, const float* __restrict__ bk,
                       const float* __restrict__ bv, const float* __restrict__ Wupd,
                       const float* __restrict__ bupd, const float* __restrict__ bedge,
                       float* __restrict__ bnp, float* __restrict__ bep) {
    int idx = blockIdx.x * 256 + threadIdx.x;
    int total = NL * (PC + ECOLS);
    if (idx >= total) return;
    int c = idx % (PC + ECOLS);
    int l = idx / (PC + ECOLS);
    if (c < PC) {
        float v = 0.f;
        if (c < 256) v = bq[l*256 + c];
        else if (c < 512) v = bk[l*256 + c - 256];
        else if (c < 1280) {
            int cc = c - 512, hd = cc / 192, p = cc % 192;
            float s = 0.f;
            for (int k = 0; k < 64; ++k) s += bv[l*256 + hd*64 + k] * Wupd[(l*192 + k)*192 + p];
            v = s;
        } else {
            int cc = c - 1280, hd = cc / 192, p = cc % 192;
            float s = 0.f;
            for (int k = 0; k < 64; ++k) s += bv[l*256 + hd*64 + k] * Wupd[(l*192 + 64 + k)*192 + p];
            v = s;
        }
        bnp[l*PC + c] = v;
    } else {
        int ce = c - PC;
        float v;
        if (ce < 256) v = bedge[l*256 + ce];
        else {
            int cc = ce - 256, hd = cc / 192, p = cc % 192;
            float s = bupd[l*192 + p];  // fold bupd here
            for (int k = 0; k < 64; ++k) s += bedge[l*256 + hd*64 + k] * Wupd[(l*192 + 128 + k)*192 + p];
            v = s;
        }
        bep[l*ECOLS + ce] = v;
    }
}

// ---------------- initial embeddings ----------------
__global__ void init_h(const float* __restrict__ x, const float* __restrict__ W_atom,
                       const float* __restrict__ b_atom, float* __restrict__ h) {
    int idx = blockIdx.x * 256 + threadIdx.x;   // N*64
    int d = idx & 63, n = idx >> 6;
    float s = b_atom[d];
    #pragma unroll
    for (int j = 0; j < 4; ++j) s += x[n*4 + j] * W_atom[j*64 + d];
    h[idx] = s;
}

__global__ void init_e(const float* __restrict__ ea, const float* __restrict__ We1,
                       const float* __restrict__ be1, const float* __restrict__ We2,
                       const float* __restrict__ be2, float* __restrict__ ef) {
    __shared__ float sT[4][64];
    int tid = threadIdx.x, d = tid & 63, sub = tid >> 6;
    int e = blockIdx.x * 4 + sub;
    float s = be1[d];
    #pragma unroll
    for (int j = 0; j < 9; ++j) s += ea[e*9 + j] * We1[j*64 + d];
    float x64 = s * 64.f;
    float sp = (x64 > 64.f) ? s : log1pf(__expf(fminf(x64, 64.f))) * (1.f/64.f);
    sT[sub][d] = sp;   // wave-local
    float acc = be2[d];
    #pragma unroll
    for (int k = 0; k < 64; ++k) acc += sT[sub][k] * We2[k*64 + d];
    ef[(size_t)e*64 + d] = acc;
}

// ---------------- MFMA projection (hi/lo split): out_bf16[rows,M] = A_f32[rows,64]@W + b ----------
#define CPAD 260
__global__ __launch_bounds__(256, 8) void proj_mfma(
    const float* __restrict__ A, const short* __restrict__ Whi, const short* __restrict__ Wlo,
    const float* __restrict__ bias, ushort* __restrict__ out, int M) {
    __shared__ short aHi[2*64*8];
    __shared__ short aLo[2*64*8];
    __shared__ ushort cTile[16*CPAD];
    int tid = threadIdx.x;
    int row0 = blockIdx.y * 16;
    int col0 = blockIdx.x * 256;
    {   // stage A: contiguous read, hi/lo split, scatter to fragment order
        int r = tid >> 4, k0 = (tid & 15) * 4;
        const float4 v = *(const float4*)(A + (size_t)(row0 + r)*64 + k0);
        int s = k0 >> 5, lane = r | (((k0 & 31) >> 3) << 4), j0 = k0 & 7;
        ushort4 hb, lb;
        hb.x = f2b(v.x); lb.x = f2b(v.x - b2fu(hb.x));
        hb.y = f2b(v.y); lb.y = f2b(v.y - b2fu(hb.y));
        hb.z = f2b(v.z); lb.z = f2b(v.z - b2fu(hb.z));
        hb.w = f2b(v.w); lb.w = f2b(v.w - b2fu(hb.w));
        *(ushort4*)&aHi[(s*64 + lane)*8 + j0] = hb;
        *(ushort4*)&aLo[(s*64 + lane)*8 + j0] = lb;
    }
    __syncthreads();
    int w = tid >> 6, lane = tid & 63;
    short8 a0h = *(const short8*)&aHi[(0*64 + lane)*8];
    short8 a1h = *(const short8*)&aHi[(1*64 + lane)*8];
    short8 a0l = *(const short8*)&aLo[(0*64 + lane)*8];
    short8 a1l = *(const short8*)&aLo[(1*64 + lane)*8];
    int cl = lane & 15, rg = lane >> 4;
    #pragma unroll
    for (int nt = 0; nt < 4; ++nt) {
        int t = (col0 >> 4) + w*4 + nt;
        const short* bph = Whi + ((size_t)(t*2)*64 + lane)*8;
        const short* bpl = Wlo + ((size_t)(t*2)*64 + lane)*8;
        short8 b0h = *(const short8*)bph;
        short8 b1h = *(const short8*)(bph + 64*8);
        short8 b0l = *(const short8*)bpl;
        short8 b1l = *(const short8*)(bpl + 64*8);
        f32x4 acc = {0.f, 0.f, 0.f, 0.f};
        acc = __builtin_amdgcn_mfma_f32_16x16x32_bf16(a0h, b0h, acc, 0, 0, 0);
        acc = __builtin_amdgcn_mfma_f32_16x16x32_bf16(a1h, b1h, acc, 0, 0, 0);
        acc = __builtin_amdgcn_mfma_f32_16x16x32_bf16(a0l, b0h, acc, 0, 0, 0);
        acc = __builtin_amdgcn_mfma_f32_16x16x32_bf16(a1l, b1h, acc, 0, 0, 0);
        acc = __builtin_amdgcn_mfma_f32_16x16x32_bf16(a0h, b0l, acc, 0, 0, 0);
        acc = __builtin_amdgcn_mfma_f32_16x16x32_bf16(a1h, b1l, acc, 0, 0, 0);
        int ccol = w*64 + nt*16 + cl;
        float bv = bias[col0 + ccol];
        #pragma unroll
        for (int r = 0; r < 4; ++r)
            cTile[(rg*4 + r)*CPAD + ccol] = f2b(acc[r] + bv);
    }
    __syncthreads();
    {   // copy out: 512B-contiguous per 16 threads
        int r = tid >> 4, cs = (tid & 15) * 16;
        ushort* dst = out + (size_t)(row0 + r)*M + col0 + cs;
        const ushort* srcp = &cTile[r*CPAD + cs];
        #pragma unroll
        for (int q = 0; q < 4; ++q)
            *(ushort4*)(dst + q*4) = *(const ushort4*)(srcp + q*4);
    }
}

// ---------------- HF = h @ Wfea + bfea (f32, residual path) ----------------
__global__ __launch_bounds__(256) void hf_proj(const float* __restrict__ h,
                                               const float* __restrict__ Wfea,
                                               const float* __restrict__ bfea,
                                               float* __restrict__ HF) {
    __shared__ float sW[64*64];
    __shared__ __align__(16) float sA[4][64];
    int tid = threadIdx.x;
    for (int i = tid; i < 4096; i += 256) sW[i] = Wfea[i];
    int c = tid & 63, no = tid >> 6;
    int n0 = blockIdx.x * 4;
    sA[no][c] = h[(size_t)(n0 + no)*64 + c];
    __syncthreads();
    float acc = bfea[c];
    #pragma unroll
    for (int k4 = 0; k4 < 16; ++k4) {
        float4 av = *(const float4*)&sA[no][k4*4];
        acc += av.x*sW[(k4*4+0)*64+c] + av.y*sW[(k4*4+1)*64+c]
             + av.z*sW[(k4*4+2)*64+c] + av.w*sW[(k4*4+3)*64+c];
    }
    HF[(size_t)(n0 + no)*64 + c] = acc;
}

// ---------------- fused per-edge attention/gating/message (MFMA msg-GEMM) ----------------
// 256 thr = 4 waves; wave hd handles head hd for all TILE=16 edges.
// Phase 1: gating -> m (bf16) to LDS. Phase 2 (same wave, no barrier): 16x16x32 MFMA
// against pre-packed Wmsg fragments, fragment-layout LN, atomic scatter-add.
__global__ __launch_bounds__(256, 6) void edge_fused(
    const bf16* __restrict__ P, const bf16* __restrict__ EP,
    const int* __restrict__ ei, int chunk_base,
    const short* __restrict__ Wmf, const float* __restrict__ bmsg,
    const float* __restrict__ g_ln, const float* __restrict__ be_ln,
    const float* __restrict__ g_msg, const float* __restrict__ be_msg,
    float* __restrict__ agg) {
    __shared__ __align__(16) ushort mld[4][TILE][KPAD];   // 25088 B
    int tid = threadIdx.x, lane = tid & 63, hd = tid >> 6;
    int e0 = blockIdx.x * TILE;
    float gl0 = g_ln[lane], gl1 = g_ln[64 + lane], gl2 = g_ln[128 + lane];
    float bl0 = be_ln[lane], bl1 = be_ln[64 + lane], bl2 = be_ln[128 + lane];
    // ---- phase 1: gating, m -> LDS (bf16) ----
    #pragma unroll 2
    for (int it = 0; it < TILE; ++it) {
        int eg = chunk_base + e0 + it;
        int src = ei[eg], dst = ei[N_EDGES + eg];
        const bf16* Pd = P + (size_t)dst * PC;
        const bf16* Ps = P + (size_t)src * PC;
        const bf16* Ee = EP + (size_t)(e0 + it) * ECOLS;
        float q  = __bfloat162float(Pd[hd*64 + lane]);
        float kd = __bfloat162float(Pd[256 + hd*64 + lane]);
        float ks = __bfloat162float(Ps[256 + hd*64 + lane]);
        float eh = __bfloat162float(Ee[hd*64 + lane]);
        float a0 = q*kd*SCALE, a1 = q*ks*SCALE, a2 = q*eh*SCALE;
        float s = a0 + a1 + a2, ss = a0*a0 + a1*a1 + a2*a2;
        #pragma unroll
        for (int m = 1; m < 64; m <<= 1) { s += __shfl_xor(s, m); ss += __shfl_xor(ss, m); }
        float mu = s * (1.f/192.f);
        float var = ss * (1.f/192.f) - mu*mu;
        float rstd = rsqrtf(var + EPSV);
        float g0 = 1.f/(1.f + __expf(-((a0 - mu)*rstd*gl0 + bl0)));
        float g1 = 1.f/(1.f + __expf(-((a1 - mu)*rstd*gl1 + bl1)));
        float g2 = 1.f/(1.f + __expf(-((a2 - mu)*rstd*gl2 + bl2)));
        float vu0 = __bfloat162float(Pd[512 + hd*192 + lane])
                  + __bfloat162float(Ps[1280 + hd*192 + lane])
                  + __bfloat162float(Ee[256 + hd*192 + lane]);
        float vu1 = __bfloat162float(Pd[512 + hd*192 + 64 + lane])
                  + __bfloat162float(Ps[1280 + hd*192 + 64 + lane])
                  + __bfloat162float(Ee[256 + hd*192 + 64 + lane]);
        float vu2 = __bfloat162float(Pd[512 + hd*192 + 128 + lane])
                  + __bfloat162float(Ps[1280 + hd*192 + 128 + lane])
                  + __bfloat162float(Ee[256 + hd*192 + 128 + lane]);
        mld[hd][it][lane]       = f2b(g0*vu0);
        mld[hd][it][64 + lane]  = f2b(g1*vu1);
        mld[hd][it][128 + lane] = f2b(g2*vu2);
    }
    // ---- phase 2: same wave reads its own head's m tile -> MFMA ----
    int cl = lane & 15, rg = lane >> 4;
    float bmsv[4], gmv[4], bmv[4];
    #pragma unroll
    for (int t = 0; t < 4; ++t) {
        bmsv[t] = bmsg[t*16 + cl];
        gmv[t]  = g_msg[t*16 + cl];
        bmv[t]  = be_msg[t*16 + cl];
    }
    int dstr[4];
    #pragma unroll
    for (int r = 0; r < 4; ++r) dstr[r] = ei[N_EDGES + chunk_base + e0 + rg*4 + r];
    f32x4 acc[4];
    #pragma unroll
    for (int t = 0; t < 4; ++t) acc[t] = (f32x4){bmsv[t], bmsv[t], bmsv[t], bmsv[t]};
    #pragma unroll
    for (int s = 0; s < 6; ++s) {
        S8U a;
        const ushort* ap = &mld[hd][cl][s*32 + rg*8];
        a.h[0] = *(const s4v*)ap;
        a.h[1] = *(const s4v*)(ap + 4);
        #pragma unroll
        for (int t = 0; t < 4; ++t) {
            short8 b = *(const short8*)&Wmf[((size_t)((t*6 + s)*64) + lane)*8];
            acc[t] = __builtin_amdgcn_mfma_f32_16x16x32_bf16(a.v, b, acc[t], 0, 0, 0);
        }
    }
    // ---- LN over 64 out-cols per edge-row (fragment layout) + scatter-add ----
    #pragma unroll
    for (int r = 0; r < 4; ++r) {
        float s1 = acc[0][r] + acc[1][r] + acc[2][r] + acc[3][r];
        float s2 = acc[0][r]*acc[0][r] + acc[1][r]*acc[1][r]
                 + acc[2][r]*acc[2][r] + acc[3][r]*acc[3][r];
        #pragma unroll
        for (int m = 1; m < 16; m <<= 1) { s1 += __shfl_xor(s1, m); s2 += __shfl_xor(s2, m); }
        float mu = s1 * (1.f/64.f);
        float var = s2 * (1.f/64.f) - mu*mu;
        float rstd = rsqrtf(var + EPSV);
        float* base = &agg[(size_t)dstr[r]*256 + hd*64];
        #pragma unroll
        for (int t = 0; t < 4; ++t)
            atomicAdd(base + t*16 + cl, (acc[t][r] - mu)*rstd*gmv[t] + bmv[t]);
    }
}

// ---------------- out = agg@Wcat + bcat, with BN partial sums ----------------
__global__ __launch_bounds__(256, 2) void agg_out(
    const float* __restrict__ agg, const float* __restrict__ Wcat, const float* __restrict__ bcat,
    float* __restrict__ out, float* __restrict__ bnsum, float* __restrict__ bnss) {
    __shared__ float sW[256 * 64];
    __shared__ __align__(16) float sA[4][256];
    __shared__ float sR[4][64];
    int tid = threadIdx.x;
    for (int i = tid; i < 256*64; i += 256) sW[i] = Wcat[i];
    int c = tid & 63, no = tid >> 6;
    float bc = bcat[c];
    float psum = 0.f, psq = 0.f;
    __syncthreads();
    int nbase = blockIdx.x * 64;
    for (int it = 0; it < 16; ++it) {
        for (int i = tid; i < 1024; i += 256)
            sA[i >> 8][i & 255] = agg[(size_t)(nbase + it*4 + (i >> 8))*256 + (i & 255)];
        __syncthreads();
        float acc = bc;
        #pragma unroll
        for (int k4 = 0; k4 < 64; ++k4) {
            float4 av = *(const float4*)&sA[no][k4*4];
            acc += av.x*sW[(k4*4+0)*64 + c] + av.y*sW[(k4*4+1)*64 + c]
                 + av.z*sW[(k4*4+2)*64 + c] + av.w*sW[(k4*4+3)*64 + c];
        }
        out[(size_t)(nbase + it*4 + no)*64 + c] = acc;
        psum += acc; psq += acc*acc;
        __syncthreads();
    }
    sR[no][c] = psum; __syncthreads();
    if (no == 0) atomicAdd(&bnsum[c], sR[0][c] + sR[1][c] + sR[2][c] + sR[3][c]);
    __syncthreads();
    sR[no][c] = psq; __syncthreads();
    if (no == 0) atomicAdd(&bnss[c], sR[0][c] + sR[1][c] + sR[2][c] + sR[3][c]);
}

// ---------------- BN finalize + silu + residual ----------------
__global__ void bn_silu(const float* __restrict__ out, const float* __restrict__ HF,
                        const float* __restrict__ bnsum, const float* __restrict__ bnss,
                        const float* __restrict__ g_bn, const float* __restrict__ be_bn,
                        float* __restrict__ h) {
    int idx = blockIdx.x * 256 + threadIdx.x;   // N*64
    int c = idx & 63;
    float mu = bnsum[c] * (1.f/N_NODES);
    float var = bnss[c] * (1.f/N_NODES) - mu*mu;
    float rstd = rsqrtf(var + EPSV);
    float v = (out[idx] - mu)*rstd*g_bn[c] + be_bn[c];
    float sv = v / (1.f + __expf(-v));
    h[idx] = sv + HF[idx];
}

// ---------------- readout ----------------
__global__ void pool_sum(const float* __restrict__ h, const int* __restrict__ batch,
                         float* __restrict__ pooled) {
    int idx = blockIdx.x * 256 + threadIdx.x;
    int n = idx >> 6, c = idx & 63;
    atomicAdd(&pooled[batch[n]*64 + c], h[idx]);
}

__global__ void pool_cnt(const int* __restrict__ batch, float* __restrict__ cntf) {
    int n = blockIdx.x * 256 + threadIdx.x;
    if (n < N_NODES) atomicAdd(&cntf[batch[n]], 1.f);
}

__global__ void head_k(const float* __restrict__ pooled, const float* __restrict__ cntf,
                       const float* __restrict__ Wfc, const float* __restrict__ bfc,
                       const float* __restrict__ Wout, const float* __restrict__ bout,
                       float* __restrict__ d_out) {
    __shared__ float red[128];
    int g = blockIdx.x, t = threadIdx.x;
    float inv = 1.f / fmaxf(cntf[g], 1.f);
    float acc = bfc[t];
    #pragma unroll
    for (int k = 0; k < 64; ++k) acc += pooled[g*64 + k]*inv*Wfc[k*128 + t];
    float z = acc / (1.f + __expf(-acc));
    red[t] = z * Wout[t];
    __syncthreads();
    for (int s1 = 64; s1 > 0; s1 >>= 1) { if (t < s1) red[t] += red[t + s1]; __syncthreads(); }
    if (t == 0) d_out[g] = red[0] + bout[0];
}

// ---------------- launcher ----------------
extern "C" void kernel_launch(void* const* d_in, const int* in_sizes, int n_in,
                              void* d_out, int out_size, void* d_ws, size_t ws_size,
                              hipStream_t stream) {
    const float* x        = (const float*)d_in[0];
    const float* edge_attr= (const float*)d_in[1];
    const int*   ei       = (const int*)  d_in[2];
    const int*   batch    = (const int*)  d_in[3];
    const float* W_atom=(const float*)d_in[4];  const float* b_atom=(const float*)d_in[5];
    const float* We1  =(const float*)d_in[6];   const float* be1  =(const float*)d_in[7];
    const float* We2  =(const float*)d_in[8];   const float* be2  =(const float*)d_in[9];
    const float* Wq   =(const float*)d_in[10];  const float* bq   =(const float*)d_in[11];
    const float* Wk   =(const float*)d_in[12];  const float* bk   =(const float*)d_in[13];
    const float* Wv   =(const float*)d_in[14];  const float* bv   =(const float*)d_in[15];
    const float* Wedge=(const float*)d_in[16];  const float* bedge=(const float*)d_in[17];
    const float* Wfea =(const float*)d_in[18];  const float* bfea =(const float*)d_in[19];
    const float* Wcat =(const float*)d_in[20];  const float* bcat =(const float*)d_in[21];
    const float* Wupd =(const float*)d_in[22];  const float* bupd =(const float*)d_in[23];
    const float* Wmsg =(const float*)d_in[24];  const float* bmsg =(const float*)d_in[25];
    const float* g_msg=(const float*)d_in[26];  const float* be_msg=(const float*)d_in[27];
    const float* g_ln =(const float*)d_in[28];  const float* be_ln=(const float*)d_in[29];
    const float* g_bn =(const float*)d_in[30];  const float* be_bn=(const float*)d_in[31];
    const float* Wfc  =(const float*)d_in[32];  const float* bfc  =(const float*)d_in[33];
    const float* Wout =(const float*)d_in[34];  const float* bout =(const float*)d_in[35];

    char* ws = (char*)d_ws;
    size_t off = 0;
    auto alloc = [&](size_t bytes) {
        void* p = ws + off;
        off += (bytes + 255) & ~(size_t)255;
        return p;
    };
    short* Wnp  = (short*)alloc((size_t)NL*2*64*PC*2);     // hi+lo planes
    float* bnp  = (float*)alloc((size_t)NL*PC*4);
    short* Wep  = (short*)alloc((size_t)NL*2*64*ECOLS*2);  // hi+lo planes
    float* bep  = (float*)alloc((size_t)NL*ECOLS*4);
    short* Wmf  = (short*)alloc((size_t)NL*12288*2);
    float* h    = (float*)alloc((size_t)N_NODES*64*4);
    float* ef   = (float*)alloc((size_t)N_EDGES*64*4);
    bf16*  P    = (bf16*) alloc((size_t)N_NODES*PC*2);
    float* HF   = (float*)alloc((size_t)N_NODES*64*4);
    float* agg  = (float*)alloc((size_t)N_NODES*256*4);
    float* bnsum= (float*)alloc(64*4);
    float* bnss = (float*)alloc(64*4);
    float* pooled=(float*)alloc(64*64*4);
    float* cntf = (float*)alloc(64*4);
    int EC = 0;
    const int cand[5] = {64000, 32000, 16000, 8000, 4000};
    for (int i = 0; i < 5; ++i) {
        size_t need = (size_t)cand[i]*ECOLS*2;
        if (off + need <= ws_size) { EC = cand[i]; break; }
    }
    if (EC == 0) return;  // workspace too small — fail visibly
    bf16* EP = (bf16*)alloc((size_t)EC*ECOLS*2);
    float* outb = (float*)EP;  // alias: EP dead when agg_out runs
    int NCHUNK = N_EDGES / EC;

    {
        int total = NL*64*(PC+ECOLS);
        pack_w<<<(total+255)/256, 256, 0, stream>>>(Wq, Wk, Wv, Wupd, Wedge, Wnp, Wep);
        int tb = NL*(PC+ECOLS);
        pack_b<<<(tb+255)/256, 256, 0, stream>>>(bq, bk, bv, Wupd, bupd, bedge, bnp, bep);
        pack_wmsg<<<(NL*192*64+255)/256, 256, 0, stream>>>(Wmsg, Wmf);
    }
    init_h<<<(N_NODES*64)/256, 256, 0, stream>>>(x, W_atom, b_atom, h);
    init_e<<<N_EDGES/4, 256, 0, stream>>>(edge_attr, We1, be1, We2, be2, ef);

    for (int l = 0; l < NL; ++l) {
        const short* Wh = Wnp + (size_t)l*2*64*PC;
        proj_mfma<<<dim3(PC/256, N_NODES/16), 256, 0, stream>>>(
            h, Wh, Wh + (size_t)64*PC, bnp + l*PC, (ushort*)P, PC);
        hf_proj<<<N_NODES/4, 256, 0, stream>>>(h, Wfea + (size_t)l*64*64, bfea + l*64, HF);
        hipMemsetAsync(agg, 0, (size_t)N_NODES*256*4, stream);
        hipMemsetAsync(bnsum, 0, 64*4, stream);
        hipMemsetAsync(bnss, 0, 64*4, stream);
        const short* Weh = Wep + (size_t)l*2*64*ECOLS;
        for (int ch = 0; ch < NCHUNK; ++ch) {
            proj_mfma<<<dim3(ECOLS/256, EC/16), 256, 0, stream>>>(
                ef + (size_t)ch*EC*64, Weh, Weh + (size_t)64*ECOLS, bep + l*ECOLS, (ushort*)EP, ECOLS);
            edge_fused<<<EC/TILE, 256, 0, stream>>>(
                P, EP, ei, ch*EC, Wmf + (size_t)l*12288, bmsg + l*64,
                g_ln + l*192, be_ln + l*192, g_msg + l*64, be_msg + l*64, agg);
        }
        agg_out<<<N_NODES/64, 256, 0, stream>>>(agg, Wcat + (size_t)l*256*64, bcat + l*64,
                                                outb, bnsum, bnss);
        bn_silu<<<(N_NODES*64)/256, 256, 0, stream>>>(outb, HF, bnsum, bnss,
                                                      g_bn + l*64, be_bn + l*64, h);
    }
    hipMemsetAsync(pooled, 0, 64*64*4, stream);
    hipMemsetAsync(cntf, 0, 64*4, stream);
    pool_sum<<<(N_NODES*64)/256, 256, 0, stream>>>(h, batch, pooled);
    pool_cnt<<<(N_NODES+255)/256, 256, 0, stream>>>(batch, cntf);
    head_k<<<N_GRAPH, 128, 0, stream>>>(pooled, cntf, Wfc, bfc, Wout, bout, (float*)d_out);
}

// Round 5
// 1658.205 us; speedup vs baseline: 3.7672x; 1.3223x over previous
//
#include <hip/hip_runtime.h>
#include <hip/hip_bf16.h>
#include <math.h>

#define N_NODES 16000
#define N_EDGES 128000
#define N_GRAPH 64
#define NL 5
#define EPSV 1e-5f
#define SCALE 0.07216878364870323f   // 1/sqrt(192)

#define PC 2048      // P cols (bf16): [0,256)=Q | [256,512)=K | [512,1280)=VdT | [1280,2048)=VsT
#define ECOLS 1024   // Wep cols: [0,256)=Eh | [256,1024)=EhT (bupd folded into bias)
#define TILE 16      // edges per block in edge_fused
#define SCR 260      // ushort stride of per-wave scratch rows

typedef __hip_bfloat16 bf16;
typedef __attribute__((ext_vector_type(8))) short short8;
typedef __attribute__((ext_vector_type(4))) short s4v;
typedef __attribute__((ext_vector_type(4))) float f32x4;
union S8U { short8 v; s4v h[2]; };

__device__ __forceinline__ ushort f2b(float x) {
    union { float f; uint u; } v; v.f = x;
    uint r = v.u + 0x7fffu + ((v.u >> 16) & 1u);   // RNE
    return (ushort)(r >> 16);
}
__device__ __forceinline__ float b2fu(ushort u) { union { uint u; float f; } v; v.u = (uint)u << 16; return v.f; }

// ---------------- weight packing (hi/lo bf16, MFMA B-fragment order) ----------------
// frag offset for W[64,M]: t=col/16, s=k/32, lane=(col&15)|(((k&31)>>3)<<4), j=k&7
__global__ void pack_w(const float* __restrict__ Wq, const float* __restrict__ Wk,
                       const float* __restrict__ Wv, const float* __restrict__ Wupd,
                       const float* __restrict__ Wedge,
                       short* __restrict__ Wnp, short* __restrict__ Wep) {
    int idx = blockIdx.x * 256 + threadIdx.x;
    int total = NL * 64 * (PC + ECOLS);
    if (idx >= total) return;
    int c = idx % (PC + ECOLS);
    int k = (idx / (PC + ECOLS)) % 64;
    int l = idx / (64 * (PC + ECOLS));
    if (c < PC) {
        float v = 0.f;
        if (c < 256) v = Wq[(l*64 + k)*256 + c];
        else if (c < 512) v = Wk[(l*64 + k)*256 + (c - 256)];
        else if (c < 1280) {
            int cc = c - 512, hd = cc / 192, p = cc % 192;
            float s = 0.f;
            for (int q = 0; q < 64; ++q)
                s += Wv[(l*64 + k)*256 + hd*64 + q] * Wupd[(l*192 + q)*192 + p];
            v = s;
        } else {
            int cc = c - 1280, hd = cc / 192, p = cc % 192;
            float s = 0.f;
            for (int q = 0; q < 64; ++q)
                s += Wv[(l*64 + k)*256 + hd*64 + q] * Wupd[(l*192 + 64 + q)*192 + p];
            v = s;
        }
        int t = c >> 4, s = k >> 5, lane = (c & 15) | (((k & 31) >> 3) << 4), jj = k & 7;
        size_t fo = ((size_t)(t*2 + s)*64 + lane)*8 + jj;
        ushort hi = f2b(v);
        ushort lo = f2b(v - b2fu(hi));
        Wnp[(size_t)l*2*64*PC + fo] = (short)hi;
        Wnp[(size_t)l*2*64*PC + (size_t)64*PC + fo] = (short)lo;
    } else {
        int ce = c - PC;
        float v;
        if (ce < 256) v = Wedge[(l*64 + k)*256 + ce];
        else {
            int cc = ce - 256, hd = cc / 192, p = cc % 192;
            float s = 0.f;
            for (int q = 0; q < 64; ++q)
                s += Wedge[(l*64 + k)*256 + hd*64 + q] * Wupd[(l*192 + 128 + q)*192 + p];
            v = s;
        }
        int t = ce >> 4, s = k >> 5, lane = (ce & 15) | (((k & 31) >> 3) << 4), jj = k & 7;
        size_t fo = ((size_t)(t*2 + s)*64 + lane)*8 + jj;
        ushort hi = f2b(v);
        ushort lo = f2b(v - b2fu(hi));
        Wep[(size_t)l*2*64*ECOLS + fo] = (short)hi;
        Wep[(size_t)l*2*64*ECOLS + (size_t)64*ECOLS + fo] = (short)lo;
    }
}

// Wmsg [192,64] per layer -> bf16 B-fragments: tile index (t*6+s), 24 tiles/layer
__global__ void pack_wmsg(const float* __restrict__ Wmsg, short* __restrict__ Wmf) {
    int idx = blockIdx.x * 256 + threadIdx.x;
    if (idx >= NL*192*64) return;
    int col = idx & 63, k = (idx >> 6) % 192, l = idx / (192*64);
    float v = Wmsg[(size_t)(l*192 + k)*64 + col];
    int t = col >> 4, s = k >> 5, lane = (col & 15) | (((k & 31) >> 3) << 4), j = k & 7;
    Wmf[(size_t)l*12288 + ((size_t)((t*6 + s)*64) + lane)*8 + j] = (short)f2b(v);
}

__global__ void pack_b(const float* __restrict__ bq, const float* __restrict__ bk,
                       const float* __restrict__ bv, const float* __restrict__ Wupd,
                       const float* __restrict__ bupd, const float* __restrict__ bedge,
                       float* __restrict__ bnp, float* __restrict__ bep) {
    int idx = blockIdx.x * 256 + threadIdx.x;
    int total = NL * (PC + ECOLS);
    if (idx >= total) return;
    int c = idx % (PC + ECOLS);
    int l = idx / (PC + ECOLS);
    if (c < PC) {
        float v = 0.f;
        if (c < 256) v = bq[l*256 + c];
        else if (c < 512) v = bk[l*256 + c - 256];
        else if (c < 1280) {
            int cc = c - 512, hd = cc / 192, p = cc % 192;
            float s = 0.f;
            for (int k = 0; k < 64; ++k) s += bv[l*256 + hd*64 + k] * Wupd[(l*192 + k)*192 + p];
            v = s;
        } else {
            int cc = c - 1280, hd = cc / 192, p = cc % 192;
            float s = 0.f;
            for (int k = 0; k < 64; ++k) s += bv[l*256 + hd*64 + k] * Wupd[(l*192 + 64 + k)*192 + p];
            v = s;
        }
        bnp[l*PC + c] = v;
    } else {
        int ce = c - PC;
        float v;
        if (ce < 256) v = bedge[l*256 + ce];
        else {
            int cc = ce - 256, hd = cc / 192, p = cc % 192;
            float s = bupd[l*192 + p];  // fold bupd here
            for (int k = 0; k < 64; ++k) s += bedge[l*256 + hd*64 + k] * Wupd[(l*192 + 128 + k)*192 + p];
            v = s;
        }
        bep[l*ECOLS + ce] = v;
    }
}

// ---------------- initial embeddings ----------------
__global__ void init_h(const float* __restrict__ x, const float* __restrict__ W_atom,
                       const float* __restrict__ b_atom, float* __restrict__ h) {
    int idx = blockIdx.x * 256 + threadIdx.x;   // N*64
    int d = idx & 63, n = idx >> 6;
    float s = b_atom[d];
    #pragma unroll
    for (int j = 0; j < 4; ++j) s += x[n*4 + j] * W_atom[j*64 + d];
    h[idx] = s;
}

__global__ void init_e(const float* __restrict__ ea, const float* __restrict__ We1,
                       const float* __restrict__ be1, const float* __restrict__ We2,
                       const float* __restrict__ be2, float* __restrict__ ef) {
    __shared__ float sT[4][64];
    int tid = threadIdx.x, d = tid & 63, sub = tid >> 6;
    int e = blockIdx.x * 4 + sub;
    float s = be1[d];
    #pragma unroll
    for (int j = 0; j < 9; ++j) s += ea[e*9 + j] * We1[j*64 + d];
    float x64 = s * 64.f;
    float sp = (x64 > 64.f) ? s : log1pf(__expf(fminf(x64, 64.f))) * (1.f/64.f);
    sT[sub][d] = sp;   // wave-local
    float acc = be2[d];
    #pragma unroll
    for (int k = 0; k < 64; ++k) acc += sT[sub][k] * We2[k*64 + d];
    ef[(size_t)e*64 + d] = acc;
}

// ---------------- MFMA projection (hi/lo split): out_bf16[rows,M] = A_f32[rows,64]@W + b ----------
#define CPAD 260
__global__ __launch_bounds__(256, 8) void proj_mfma(
    const float* __restrict__ A, const short* __restrict__ Whi, const short* __restrict__ Wlo,
    const float* __restrict__ bias, ushort* __restrict__ out, int M) {
    __shared__ short aHi[2*64*8];
    __shared__ short aLo[2*64*8];
    __shared__ ushort cTile[16*CPAD];
    int tid = threadIdx.x;
    int row0 = blockIdx.y * 16;
    int col0 = blockIdx.x * 256;
    {   // stage A: contiguous read, hi/lo split, scatter to fragment order
        int r = tid >> 4, k0 = (tid & 15) * 4;
        const float4 v = *(const float4*)(A + (size_t)(row0 + r)*64 + k0);
        int s = k0 >> 5, lane = r | (((k0 & 31) >> 3) << 4), j0 = k0 & 7;
        ushort4 hb, lb;
        hb.x = f2b(v.x); lb.x = f2b(v.x - b2fu(hb.x));
        hb.y = f2b(v.y); lb.y = f2b(v.y - b2fu(hb.y));
        hb.z = f2b(v.z); lb.z = f2b(v.z - b2fu(hb.z));
        hb.w = f2b(v.w); lb.w = f2b(v.w - b2fu(hb.w));
        *(ushort4*)&aHi[(s*64 + lane)*8 + j0] = hb;
        *(ushort4*)&aLo[(s*64 + lane)*8 + j0] = lb;
    }
    __syncthreads();
    int w = tid >> 6, lane = tid & 63;
    short8 a0h = *(const short8*)&aHi[(0*64 + lane)*8];
    short8 a1h = *(const short8*)&aHi[(1*64 + lane)*8];
    short8 a0l = *(const short8*)&aLo[(0*64 + lane)*8];
    short8 a1l = *(const short8*)&aLo[(1*64 + lane)*8];
    int cl = lane & 15, rg = lane >> 4;
    #pragma unroll
    for (int nt = 0; nt < 4; ++nt) {
        int t = (col0 >> 4) + w*4 + nt;
        const short* bph = Whi + ((size_t)(t*2)*64 + lane)*8;
        const short* bpl = Wlo + ((size_t)(t*2)*64 + lane)*8;
        short8 b0h = *(const short8*)bph;
        short8 b1h = *(const short8*)(bph + 64*8);
        short8 b0l = *(const short8*)bpl;
        short8 b1l = *(const short8*)(bpl + 64*8);
        f32x4 acc = {0.f, 0.f, 0.f, 0.f};
        acc = __builtin_amdgcn_mfma_f32_16x16x32_bf16(a0h, b0h, acc, 0, 0, 0);
        acc = __builtin_amdgcn_mfma_f32_16x16x32_bf16(a1h, b1h, acc, 0, 0, 0);
        acc = __builtin_amdgcn_mfma_f32_16x16x32_bf16(a0l, b0h, acc, 0, 0, 0);
        acc = __builtin_amdgcn_mfma_f32_16x16x32_bf16(a1l, b1h, acc, 0, 0, 0);
        acc = __builtin_amdgcn_mfma_f32_16x16x32_bf16(a0h, b0l, acc, 0, 0, 0);
        acc = __builtin_amdgcn_mfma_f32_16x16x32_bf16(a1h, b1l, acc, 0, 0, 0);
        int ccol = w*64 + nt*16 + cl;
        float bv = bias[col0 + ccol];
        #pragma unroll
        for (int r = 0; r < 4; ++r)
            cTile[(rg*4 + r)*CPAD + ccol] = f2b(acc[r] + bv);
    }
    __syncthreads();
    {   // copy out: 512B-contiguous per 16 threads
        int r = tid >> 4, cs = (tid & 15) * 16;
        ushort* dst = out + (size_t)(row0 + r)*M + col0 + cs;
        const ushort* srcp = &cTile[r*CPAD + cs];
        #pragma unroll
        for (int q = 0; q < 4; ++q)
            *(ushort4*)(dst + q*4) = *(const ushort4*)(srcp + q*4);
    }
}

// ---------------- HF = h @ Wfea + bfea (f32, residual path) ----------------
__global__ __launch_bounds__(256) void hf_proj(const float* __restrict__ h,
                                               const float* __restrict__ Wfea,
                                               const float* __restrict__ bfea,
                                               float* __restrict__ HF) {
    __shared__ float sW[64*64];
    __shared__ __align__(16) float sA[4][64];
    int tid = threadIdx.x;
    for (int i = tid; i < 4096; i += 256) sW[i] = Wfea[i];
    int c = tid & 63, no = tid >> 6;
    int n0 = blockIdx.x * 4;
    sA[no][c] = h[(size_t)(n0 + no)*64 + c];
    __syncthreads();
    float acc = bfea[c];
    #pragma unroll
    for (int k4 = 0; k4 < 16; ++k4) {
        float4 av = *(const float4*)&sA[no][k4*4];
        acc += av.x*sW[(k4*4+0)*64+c] + av.y*sW[(k4*4+1)*64+c]
             + av.z*sW[(k4*4+2)*64+c] + av.w*sW[(k4*4+3)*64+c];
    }
    HF[(size_t)(n0 + no)*64 + c] = acc;
}

// ---------------- fused per-edge: EP-projection (MFMA) + gating + msg-GEMM (MFMA) -------------
// 256 thr = 4 waves; wave hd owns head hd for TILE=16 edges.
// Phase 0: EP tile (Eh|EhT for this head) = ef_tile @ Wep via MFMA -> per-wave LDS scratch.
// Phase 1: gating math; reads Eh/EhT from scratch, writes m in-place over EhT slots.
// Phase 2: msg-GEMM via MFMA, fragment-layout LN, atomic scatter-add.
__global__ __launch_bounds__(256, 4) void edge_fused(
    const bf16* __restrict__ P, const float* __restrict__ ef,
    const short* __restrict__ Wef, const float* __restrict__ bef,
    const int* __restrict__ ei,
    const short* __restrict__ Wmf, const float* __restrict__ bmsg,
    const float* __restrict__ g_ln, const float* __restrict__ be_ln,
    const float* __restrict__ g_msg, const float* __restrict__ be_msg,
    float* __restrict__ agg) {
    __shared__ short aHi[2*64*8];                       // 2 KB
    __shared__ short aLo[2*64*8];                       // 2 KB
    __shared__ __align__(16) ushort scr[4][TILE][SCR];  // 33.3 KB: per-wave [Eh 0..64 | EhT/m 64..256)
    int tid = threadIdx.x, lane = tid & 63, hd = tid >> 6;
    int e0 = blockIdx.x * TILE;
    {   // stage A = ef tile (16 edges x 64 k), hi/lo fragment order
        int r = tid >> 4, k0 = (tid & 15) * 4;
        const float4 v = *(const float4*)(ef + (size_t)(e0 + r)*64 + k0);
        int s = k0 >> 5, alane = r | (((k0 & 31) >> 3) << 4), j0 = k0 & 7;
        ushort4 hb, lb;
        hb.x = f2b(v.x); lb.x = f2b(v.x - b2fu(hb.x));
        hb.y = f2b(v.y); lb.y = f2b(v.y - b2fu(hb.y));
        hb.z = f2b(v.z); lb.z = f2b(v.z - b2fu(hb.z));
        hb.w = f2b(v.w); lb.w = f2b(v.w - b2fu(hb.w));
        *(ushort4*)&aHi[(s*64 + alane)*8 + j0] = hb;
        *(ushort4*)&aLo[(s*64 + alane)*8 + j0] = lb;
    }
    __syncthreads();
    int cl = lane & 15, rg = lane >> 4;
    // ---- phase 0: this head's EP tile -> scratch ----
    {
        short8 a0h = *(const short8*)&aHi[(0*64 + lane)*8];
        short8 a1h = *(const short8*)&aHi[(1*64 + lane)*8];
        short8 a0l = *(const short8*)&aLo[(0*64 + lane)*8];
        short8 a1l = *(const short8*)&aLo[(1*64 + lane)*8];
        #pragma unroll
        for (int tt = 0; tt < 16; ++tt) {
            int tg = (tt < 4) ? (hd*4 + tt) : (16 + hd*12 + (tt - 4));
            const short* bph = Wef + ((size_t)(tg*2)*64 + lane)*8;
            const short* bpl = bph + (size_t)64*ECOLS;
            short8 b0h = *(const short8*)bph;
            short8 b1h = *(const short8*)(bph + 512);
            short8 b0l = *(const short8*)bpl;
            short8 b1l = *(const short8*)(bpl + 512);
            float bv = bef[tg*16 + cl];
            f32x4 acc = {bv, bv, bv, bv};
            acc = __builtin_amdgcn_mfma_f32_16x16x32_bf16(a0h, b0h, acc, 0, 0, 0);
            acc = __builtin_amdgcn_mfma_f32_16x16x32_bf16(a1h, b1h, acc, 0, 0, 0);
            acc = __builtin_amdgcn_mfma_f32_16x16x32_bf16(a0l, b0h, acc, 0, 0, 0);
            acc = __builtin_amdgcn_mfma_f32_16x16x32_bf16(a1l, b1h, acc, 0, 0, 0);
            acc = __builtin_amdgcn_mfma_f32_16x16x32_bf16(a0h, b0l, acc, 0, 0, 0);
            acc = __builtin_amdgcn_mfma_f32_16x16x32_bf16(a1h, b1l, acc, 0, 0, 0);
            int wcol = (tt < 4) ? (tt*16 + cl) : (64 + (tt - 4)*16 + cl);
            #pragma unroll
            for (int r = 0; r < 4; ++r)
                scr[hd][rg*4 + r][wcol] = f2b(acc[r]);
        }
    }
    // ---- phase 1: gating; m overwrites EhT slots (wave-local, per-lane RAW-safe) ----
    float gl0 = g_ln[lane], gl1 = g_ln[64 + lane], gl2 = g_ln[128 + lane];
    float bl0 = be_ln[lane], bl1 = be_ln[64 + lane], bl2 = be_ln[128 + lane];
    #pragma unroll 2
    for (int it = 0; it < TILE; ++it) {
        int eg = e0 + it;
        int src = ei[eg], dst = ei[N_EDGES + eg];
        const bf16* Pd = P + (size_t)dst * PC;
        const bf16* Ps = P + (size_t)src * PC;
        float q  = __bfloat162float(Pd[hd*64 + lane]);
        float kd = __bfloat162float(Pd[256 + hd*64 + lane]);
        float ks = __bfloat162float(Ps[256 + hd*64 + lane]);
        float eh = b2fu(scr[hd][it][lane]);
        float a0 = q*kd*SCALE, a1 = q*ks*SCALE, a2 = q*eh*SCALE;
        float s = a0 + a1 + a2, ss = a0*a0 + a1*a1 + a2*a2;
        #pragma unroll
        for (int m = 1; m < 64; m <<= 1) { s += __shfl_xor(s, m); ss += __shfl_xor(ss, m); }
        float mu = s * (1.f/192.f);
        float var = ss * (1.f/192.f) - mu*mu;
        float rstd = rsqrtf(var + EPSV);
        float g0 = 1.f/(1.f + __expf(-((a0 - mu)*rstd*gl0 + bl0)));
        float g1 = 1.f/(1.f + __expf(-((a1 - mu)*rstd*gl1 + bl1)));
        float g2 = 1.f/(1.f + __expf(-((a2 - mu)*rstd*gl2 + bl2)));
        float vu0 = __bfloat162float(Pd[512 + hd*192 + lane])
                  + __bfloat162float(Ps[1280 + hd*192 + lane])
                  + b2fu(scr[hd][it][64 + lane]);
        float vu1 = __bfloat162float(Pd[512 + hd*192 + 64 + lane])
                  + __bfloat162float(Ps[1280 + hd*192 + 64 + lane])
                  + b2fu(scr[hd][it][128 + lane]);
        float vu2 = __bfloat162float(Pd[512 + hd*192 + 128 + lane])
                  + __bfloat162float(Ps[1280 + hd*192 + 128 + lane])
                  + b2fu(scr[hd][it][192 + lane]);
        scr[hd][it][64 + lane]  = f2b(g0*vu0);
        scr[hd][it][128 + lane] = f2b(g1*vu1);
        scr[hd][it][192 + lane] = f2b(g2*vu2);
    }
    // ---- phase 2: msg-GEMM (m tile @ Wmsg) + fragment-layout LN + scatter ----
    float bmsv[4], gmv[4], bmv[4];
    #pragma unroll
    for (int t = 0; t < 4; ++t) {
        bmsv[t] = bmsg[t*16 + cl];
        gmv[t]  = g_msg[t*16 + cl];
        bmv[t]  = be_msg[t*16 + cl];
    }
    int dstr[4];
    #pragma unroll
    for (int r = 0; r < 4; ++r) dstr[r] = ei[N_EDGES + e0 + rg*4 + r];
    f32x4 acc[4];
    #pragma unroll
    for (int t = 0; t < 4; ++t) acc[t] = (f32x4){bmsv[t], bmsv[t], bmsv[t], bmsv[t]};
    #pragma unroll
    for (int s = 0; s < 6; ++s) {
        S8U a;
        const ushort* ap = &scr[hd][cl][64 + s*32 + rg*8];
        a.h[0] = *(const s4v*)ap;
        a.h[1] = *(const s4v*)(ap + 4);
        #pragma unroll
        for (int t = 0; t < 4; ++t) {
            short8 b = *(const short8*)&Wmf[((size_t)((t*6 + s)*64) + lane)*8];
            acc[t] = __builtin_amdgcn_mfma_f32_16x16x32_bf16(a.v, b, acc[t], 0, 0, 0);
        }
    }
    #pragma unroll
    for (int r = 0; r < 4; ++r) {
        float s1 = acc[0][r] + acc[1][r] + acc[2][r] + acc[3][r];
        float s2 = acc[0][r]*acc[0][r] + acc[1][r]*acc[1][r]
                 + acc[2][r]*acc[2][r] + acc[3][r]*acc[3][r];
        #pragma unroll
        for (int m = 1; m < 16; m <<= 1) { s1 += __shfl_xor(s1, m); s2 += __shfl_xor(s2, m); }
        float mu = s1 * (1.f/64.f);
        float var = s2 * (1.f/64.f) - mu*mu;
        float rstd = rsqrtf(var + EPSV);
        float* base = &agg[(size_t)dstr[r]*256 + hd*64];
        #pragma unroll
        for (int t = 0; t < 4; ++t)
            atomicAdd(base + t*16 + cl, (acc[t][r] - mu)*rstd*gmv[t] + bmv[t]);
    }
}

// ---------------- out = agg@Wcat + bcat, with BN partial sums ----------------
__global__ __launch_bounds__(256, 2) void agg_out(
    const float* __restrict__ agg, const float* __restrict__ Wcat, const float* __restrict__ bcat,
    float* __restrict__ out, float* __restrict__ bnsum, float* __restrict__ bnss) {
    __shared__ float sW[256 * 64];
    __shared__ __align__(16) float sA[4][256];
    __shared__ float sR[4][64];
    int tid = threadIdx.x;
    for (int i = tid; i < 256*64; i += 256) sW[i] = Wcat[i];
    int c = tid & 63, no = tid >> 6;
    float bc = bcat[c];
    float psum = 0.f, psq = 0.f;
    __syncthreads();
    int nbase = blockIdx.x * 64;
    for (int it = 0; it < 16; ++it) {
        for (int i = tid; i < 1024; i += 256)
            sA[i >> 8][i & 255] = agg[(size_t)(nbase + it*4 + (i >> 8))*256 + (i & 255)];
        __syncthreads();
        float acc = bc;
        #pragma unroll
        for (int k4 = 0; k4 < 64; ++k4) {
            float4 av = *(const float4*)&sA[no][k4*4];
            acc += av.x*sW[(k4*4+0)*64 + c] + av.y*sW[(k4*4+1)*64 + c]
                 + av.z*sW[(k4*4+2)*64 + c] + av.w*sW[(k4*4+3)*64 + c];
        }
        out[(size_t)(nbase + it*4 + no)*64 + c] = acc;
        psum += acc; psq += acc*acc;
        __syncthreads();
    }
    sR[no][c] = psum; __syncthreads();
    if (no == 0) atomicAdd(&bnsum[c], sR[0][c] + sR[1][c] + sR[2][c] + sR[3][c]);
    __syncthreads();
    sR[no][c] = psq; __syncthreads();
    if (no == 0) atomicAdd(&bnss[c], sR[0][c] + sR[1][c] + sR[2][c] + sR[3][c]);
}

// ---------------- BN finalize + silu + residual ----------------
__global__ void bn_silu(const float* __restrict__ out, const float* __restrict__ HF,
                        const float* __restrict__ bnsum, const float* __restrict__ bnss,
                        const float* __restrict__ g_bn, const float* __restrict__ be_bn,
                        float* __restrict__ h) {
    int idx = blockIdx.x * 256 + threadIdx.x;   // N*64
    int c = idx & 63;
    float mu = bnsum[c] * (1.f/N_NODES);
    float var = bnss[c] * (1.f/N_NODES) - mu*mu;
    float rstd = rsqrtf(var + EPSV);
    float v = (out[idx] - mu)*rstd*g_bn[c] + be_bn[c];
    float sv = v / (1.f + __expf(-v));
    h[idx] = sv + HF[idx];
}

// ---------------- fused readout: segment mean (sorted batch) + MLP head ----------------
__device__ __forceinline__ int lbound(const int* __restrict__ a, int n, int v) {
    int lo = 0, hi = n;
    while (lo < hi) { int m = (lo + hi) >> 1; if (a[m] < v) lo = m + 1; else hi = m; }
    return lo;
}

__global__ __launch_bounds__(256) void pool_head(
    const float* __restrict__ h, const int* __restrict__ batch,
    const float* __restrict__ Wfc, const float* __restrict__ bfc,
    const float* __restrict__ Wout, const float* __restrict__ bout,
    float* __restrict__ d_out) {
    __shared__ float sPart[4][64];
    __shared__ float sP[64];
    __shared__ float red[128];
    int g = blockIdx.x, tid = threadIdx.x;
    int lo = lbound(batch, N_NODES, g);
    int hi = lbound(batch, N_NODES, g + 1);
    int c = tid & 63, rg = tid >> 6;
    float s = 0.f;
    for (int n = lo + rg; n < hi; n += 4) s += h[(size_t)n*64 + c];
    sPart[rg][c] = s;
    __syncthreads();
    if (tid < 64)
        sP[tid] = (sPart[0][tid] + sPart[1][tid] + sPart[2][tid] + sPart[3][tid])
                  * (1.f / fmaxf((float)(hi - lo), 1.f));
    __syncthreads();
    if (tid < 128) {
        float acc = bfc[tid];
        #pragma unroll
        for (int k = 0; k < 64; ++k) acc += sP[k] * Wfc[k*128 + tid];
        float z = acc / (1.f + __expf(-acc));
        red[tid] = z * Wout[tid];
    }
    __syncthreads();
    for (int s1 = 64; s1 > 0; s1 >>= 1) {
        if (tid < s1 && tid + s1 < 128) red[tid] += red[tid + s1];
        __syncthreads();
    }
    if (tid == 0) d_out[g] = red[0] + bout[0];
}

// ---------------- launcher ----------------
extern "C" void kernel_launch(void* const* d_in, const int* in_sizes, int n_in,
                              void* d_out, int out_size, void* d_ws, size_t ws_size,
                              hipStream_t stream) {
    const float* x        = (const float*)d_in[0];
    const float* edge_attr= (const float*)d_in[1];
    const int*   ei       = (const int*)  d_in[2];
    const int*   batch    = (const int*)  d_in[3];
    const float* W_atom=(const float*)d_in[4];  const float* b_atom=(const float*)d_in[5];
    const float* We1  =(const float*)d_in[6];   const float* be1  =(const float*)d_in[7];
    const float* We2  =(const float*)d_in[8];   const float* be2  =(const float*)d_in[9];
    const float* Wq   =(const float*)d_in[10];  const float* bq   =(const float*)d_in[11];
    const float* Wk   =(const float*)d_in[12];  const float* bk   =(const float*)d_in[13];
    const float* Wv   =(const float*)d_in[14];  const float* bv   =(const float*)d_in[15];
    const float* Wedge=(const float*)d_in[16];  const float* bedge=(const float*)d_in[17];
    const float* Wfea =(const float*)d_in[18];  const float* bfea =(const float*)d_in[19];
    const float* Wcat =(const float*)d_in[20];  const float* bcat =(const float*)d_in[21];
    const float* Wupd =(const float*)d_in[22];  const float* bupd =(const float*)d_in[23];
    const float* Wmsg =(const float*)d_in[24];  const float* bmsg =(const float*)d_in[25];
    const float* g_msg=(const float*)d_in[26];  const float* be_msg=(const float*)d_in[27];
    const float* g_ln =(const float*)d_in[28];  const float* be_ln=(const float*)d_in[29];
    const float* g_bn =(const float*)d_in[30];  const float* be_bn=(const float*)d_in[31];
    const float* Wfc  =(const float*)d_in[32];  const float* bfc  =(const float*)d_in[33];
    const float* Wout =(const float*)d_in[34];  const float* bout =(const float*)d_in[35];

    char* ws = (char*)d_ws;
    size_t off = 0;
    auto alloc = [&](size_t bytes) {
        void* p = ws + off;
        off += (bytes + 255) & ~(size_t)255;
        return p;
    };
    short* Wnp  = (short*)alloc((size_t)NL*2*64*PC*2);     // hi+lo planes
    float* bnp  = (float*)alloc((size_t)NL*PC*4);
    short* Wep  = (short*)alloc((size_t)NL*2*64*ECOLS*2);  // hi+lo planes
    float* bep  = (float*)alloc((size_t)NL*ECOLS*4);
    short* Wmf  = (short*)alloc((size_t)NL*12288*2);
    float* h    = (float*)alloc((size_t)N_NODES*64*4);
    float* ef   = (float*)alloc((size_t)N_EDGES*64*4);
    bf16*  P    = (bf16*) alloc((size_t)N_NODES*PC*2);
    float* HF   = (float*)alloc((size_t)N_NODES*64*4);
    float* agg  = (float*)alloc((size_t)N_NODES*256*4);
    float* outb = (float*)alloc((size_t)N_NODES*64*4);
    float* bnsum= (float*)alloc(64*4);
    float* bnss = (float*)alloc(64*4);
    if (off > ws_size) return;  // fail visibly

    {
        int total = NL*64*(PC+ECOLS);
        pack_w<<<(total+255)/256, 256, 0, stream>>>(Wq, Wk, Wv, Wupd, Wedge, Wnp, Wep);
        int tb = NL*(PC+ECOLS);
        pack_b<<<(tb+255)/256, 256, 0, stream>>>(bq, bk, bv, Wupd, bupd, bedge, bnp, bep);
        pack_wmsg<<<(NL*192*64+255)/256, 256, 0, stream>>>(Wmsg, Wmf);
    }
    init_h<<<(N_NODES*64)/256, 256, 0, stream>>>(x, W_atom, b_atom, h);
    init_e<<<N_EDGES/4, 256, 0, stream>>>(edge_attr, We1, be1, We2, be2, ef);

    for (int l = 0; l < NL; ++l) {
        const short* Wh = Wnp + (size_t)l*2*64*PC;
        proj_mfma<<<dim3(PC/256, N_NODES/16), 256, 0, stream>>>(
            h, Wh, Wh + (size_t)64*PC, bnp + l*PC, (ushort*)P, PC);
        hf_proj<<<N_NODES/4, 256, 0, stream>>>(h, Wfea + (size_t)l*64*64, bfea + l*64, HF);
        hipMemsetAsync(agg, 0, (size_t)N_NODES*256*4, stream);
        hipMemsetAsync(bnsum, 0, 64*4, stream);
        hipMemsetAsync(bnss, 0, 64*4, stream);
        edge_fused<<<N_EDGES/TILE, 256, 0, stream>>>(
            P, ef, Wep + (size_t)l*2*64*ECOLS, bep + l*ECOLS, ei,
            Wmf + (size_t)l*12288, bmsg + l*64,
            g_ln + l*192, be_ln + l*192, g_msg + l*64, be_msg + l*64, agg);
        agg_out<<<N_NODES/64, 256, 0, stream>>>(agg, Wcat + (size_t)l*256*64, bcat + l*64,
                                                outb, bnsum, bnss);
        bn_silu<<<(N_NODES*64)/256, 256, 0, stream>>>(outb, HF, bnsum, bnss,
                                                      g_bn + l*64, be_bn + l*64, h);
    }
    pool_head<<<N_GRAPH, 256, 0, stream>>>(h, batch, Wfc, bfc, Wout, bout, (float*)d_out);
}